// Round 6
// baseline (337.280 us; speedup 1.0000x reference)
//
#include <hip/hip_runtime.h>
#include <stdint.h>

// Problem constants
#define B_SZ 4
#define L_SEQ 8192
#define D_CH 768
#define K_F 24
#define NFFT2 8192       // FFT size after parity split (2*4096)
#define LDS_BYTES 69632  // 8704 float2 (padded: phi(i) = i + (i>>4))
#define GEMM_LDS 131072  // As 2x16KB + Bs 3x32KB

typedef __attribute__((ext_vector_type(4))) float f32x4;
typedef __attribute__((ext_vector_type(8))) __bf16 bf16x8;

// twiddle table offsets (float2 units): [h=1024:1024x8][h=128:128x8][h=16:16x8][h=2:2x8]
#define TW1024 0
#define TW128 8192
#define TW16 9216
#define TW2 9344
#define TW_TOTAL 9360

// ---------- bf16 helpers (RNE) ----------
__device__ __forceinline__ uint32_t f2bf1(float f) {
  uint32_t u = __float_as_uint(f);
  return (u + 0x7fffu + ((u >> 16) & 1u)) >> 16;
}
__device__ __forceinline__ uint32_t packbf2(float lo, float hi) {
  return f2bf1(lo) | (f2bf1(hi) << 16);
}
__device__ __forceinline__ float2 unpackbf2(uint32_t v) {
  return float2{__uint_as_float(v << 16), __uint_as_float(v & 0xffff0000u)};
}
__device__ __forceinline__ float2 cmulf(float2 a, float2 b) {
  return float2{a.x * b.x - a.y * b.y, a.x * b.y + a.y * b.x};
}
__device__ __forceinline__ float2 cmulc(float2 a, float2 b) {  // a * conj(b)
  return float2{a.x * b.x + a.y * b.y, a.y * b.x - a.x * b.y};
}
__device__ __forceinline__ uint32_t pkbf(float lo, float hi) {
  uint32_t r;
  asm("v_cvt_pk_bf16_f32 %0, %1, %2" : "=v"(r) : "v"(lo), "v"(hi));
  return r;
}

// ---------- twiddle table build (once, 9360 entries, fp64 sincos) ----------
__global__ __launch_bounds__(256) void k_tw(float2* __restrict__ TW) {
  int i = blockIdx.x * 256 + threadIdx.x;
  if (i >= TW_TOTAL) return;
  int e = i >> 3, q = i & 7;
  int h, pos;
  if (e < 1024) { h = 1024; pos = e; }
  else if (e < 1152) { h = 128; pos = e - 1024; }
  else if (e < 1168) { h = 16; pos = e - 1152; }
  else { h = 2; pos = e - 1168; }
  double ang = -6.28318530717958647692 * (double)(pos * q) / (double)(8 * h);
  TW[i] = float2{(float)cos(ang), (float)sin(ang)};
}

// MiT[n][e] = Mi[e][n], bf16
__global__ __launch_bounds__(256) void k_mit(const float* __restrict__ Mi,
                                             uint16_t* __restrict__ MiT) {
  int i = blockIdx.x * 256 + threadIdx.x;  // = n*768 + e
  int n = i / 768, e = i - n * 768;
  MiT[i] = (uint16_t)f2bf1(Mi[e * 768 + n]);
}

// ---------- radix-8 DFT building block ----------
template <int S>
__device__ __forceinline__ void dft8(float2* x) {
  const float C = 0.70710678118654752f;
  float2 t0{x[0].x + x[4].x, x[0].y + x[4].y}, t1{x[0].x - x[4].x, x[0].y - x[4].y};
  float2 t2{x[2].x + x[6].x, x[2].y + x[6].y}, t3{x[2].x - x[6].x, x[2].y - x[6].y};
  float2 t4{x[1].x + x[5].x, x[1].y + x[5].y}, t5{x[1].x - x[5].x, x[1].y - x[5].y};
  float2 t6{x[3].x + x[7].x, x[3].y + x[7].y}, t7{x[3].x - x[7].x, x[3].y - x[7].y};
  float2 t3r = (S < 0) ? float2{t3.y, -t3.x} : float2{-t3.y, t3.x};
  float2 t7r = (S < 0) ? float2{t7.y, -t7.x} : float2{-t7.y, t7.x};
  float2 e0{t0.x + t2.x, t0.y + t2.y}, e2{t0.x - t2.x, t0.y - t2.y};
  float2 e1{t1.x + t3r.x, t1.y + t3r.y}, e3{t1.x - t3r.x, t1.y - t3r.y};
  float2 o0{t4.x + t6.x, t4.y + t6.y}, o2{t4.x - t6.x, t4.y - t6.y};
  float2 o1{t5.x + t7r.x, t5.y + t7r.y}, o3{t5.x - t7r.x, t5.y - t7r.y};
  float2 o1r = (S < 0) ? float2{C * (o1.x + o1.y), C * (o1.y - o1.x)}
                       : float2{C * (o1.x - o1.y), C * (o1.y + o1.x)};
  float2 o2r = (S < 0) ? float2{o2.y, -o2.x} : float2{-o2.y, o2.x};
  float2 o3r = (S < 0) ? float2{C * (o3.y - o3.x), -C * (o3.x + o3.y)}
                       : float2{-C * (o3.x + o3.y), C * (o3.x - o3.y)};
  x[0] = float2{e0.x + o0.x, e0.y + o0.y};
  x[4] = float2{e0.x - o0.x, e0.y - o0.y};
  x[1] = float2{e1.x + o1r.x, e1.y + o1r.y};
  x[5] = float2{e1.x - o1r.x, e1.y - o1r.y};
  x[2] = float2{e2.x + o2r.x, e2.y + o2r.y};
  x[6] = float2{e2.x - o2r.x, e2.y - o2r.y};
  x[3] = float2{e3.x + o3r.x, e3.y + o3r.y};
  x[7] = float2{e3.x - o3r.x, e3.y - o3r.y};
}

#define TWLOAD(tw, pos)                                            \
  const float4* tp_ = (const float4*)((tw) + ((size_t)(pos) << 3)); \
  float4 t01 = tp_[0], t23 = tp_[1], t45 = tp_[2], t67 = tp_[3];   \
  float2 w1{t01.z, t01.w}, w2{t23.x, t23.y}, w3{t23.z, t23.w},     \
      w4{t45.x, t45.y}, w5{t45.z, t45.w}, w6{t67.x, t67.y}, w7{t67.z, t67.w};

// Generic radix-8 LDS pass, padded layout, table twiddles.
template <int LH, int S, int NT>
__device__ __forceinline__ void pass_r8t(float2* a, const float2* __restrict__ tw, int tid) {
  constexpr int h = 1 << LH;
  constexpr int st = h + (h >> 4);
  __syncthreads();
#pragma unroll
  for (int jj = 0; jj < 1024 / NT; ++jj) {
    int j = jj * NT + tid;
    int pos = j & (h - 1);
    int base = ((j >> LH) << (LH + 3)) + pos;
    float2* p = a + (base + (base >> 4));
    TWLOAD(tw, pos);
    float2 x[8];
#pragma unroll
    for (int q = 0; q < 8; ++q) x[q] = p[q * st];
    if constexpr (S < 0) {
      dft8<-1>(x);
      x[1] = cmulf(x[1], w1); x[2] = cmulf(x[2], w2); x[3] = cmulf(x[3], w3);
      x[4] = cmulf(x[4], w4); x[5] = cmulf(x[5], w5); x[6] = cmulf(x[6], w6);
      x[7] = cmulf(x[7], w7);
    } else {
      x[1] = cmulc(x[1], w1); x[2] = cmulc(x[2], w2); x[3] = cmulc(x[3], w3);
      x[4] = cmulc(x[4], w4); x[5] = cmulc(x[5], w5); x[6] = cmulc(x[6], w6);
      x[7] = cmulc(x[7], w7);
      dft8<1>(x);
    }
#pragma unroll
    for (int q = 0; q < 8; ++q) p[q * st] = x[q];
  }
}

// Fused first forward pass (h=1024): bf16 row from global, upper half zero.
__device__ __forceinline__ void p1_fused(float2* a, const uint32_t* __restrict__ row32,
                                         const float2* __restrict__ tw, int tid) {
#pragma unroll
  for (int jj = 0; jj < 2; ++jj) {
    int j = jj * 512 + tid;
    TWLOAD(tw, j);
    float2 x[8];
#pragma unroll
    for (int q = 0; q < 4; ++q) x[q] = unpackbf2(row32[j + q * 1024]);
    x[4] = x[5] = x[6] = x[7] = float2{0.f, 0.f};
    dft8<-1>(x);
    x[1] = cmulf(x[1], w1); x[2] = cmulf(x[2], w2); x[3] = cmulf(x[3], w3);
    x[4] = cmulf(x[4], w4); x[5] = cmulf(x[5], w5); x[6] = cmulf(x[6], w6);
    x[7] = cmulf(x[7], w7);
    float2* p = a + (j + (j >> 4));
#pragma unroll
    for (int q = 0; q < 8; ++q) p[q * 1088] = x[q];
  }
}

// Fused middle: forward r2 + *W2 + inverse r2
__device__ __forceinline__ void mid_fused(float2* a, const uint32_t* __restrict__ wrow, int tid) {
  __syncthreads();
#pragma unroll
  for (int jj = 0; jj < 8; ++jj) {
    int j = jj * 512 + tid;
    float2* p = a + (2 * j + ((2 * j) >> 4));
    float2 u = p[0], v = p[1];
    float2 s{u.x + v.x, u.y + v.y}, dd{u.x - v.x, u.y - v.y};
    uint2 wv = *(const uint2*)(wrow + 2 * j);
    s = cmulf(s, unpackbf2(wv.x));
    dd = cmulf(dd, unpackbf2(wv.y));
    p[0] = float2{s.x + dd.x, s.y + dd.y};
    p[1] = float2{s.x - dd.x, s.y - dd.y};
  }
}

// Fused last inverse pass (h=1024): pack bf16 + store first 4096 outputs.
__device__ __forceinline__ void last_fused(float2* a, uint32_t* __restrict__ out32,
                                           const float2* __restrict__ tw, int tid) {
  __syncthreads();
#pragma unroll
  for (int jj = 0; jj < 2; ++jj) {
    int j = jj * 512 + tid;
    TWLOAD(tw, j);
    float2* p = a + (j + (j >> 4));
    float2 x[8];
#pragma unroll
    for (int q = 0; q < 8; ++q) x[q] = p[q * 1088];
    x[1] = cmulc(x[1], w1); x[2] = cmulc(x[2], w2); x[3] = cmulc(x[3], w3);
    x[4] = cmulc(x[4], w4); x[5] = cmulc(x[5], w5); x[6] = cmulc(x[6], w6);
    x[7] = cmulc(x[7], w7);
    dft8<1>(x);
#pragma unroll
    for (int q = 0; q < 4; ++q) out32[j + q * 1024] = packbf2(x[q].x, x[q].y);
  }
}

// Phi2[k][f] = fwd-FFT( pad( (2/8192)*phi[2r,k], r<4096 ) ), scrambled order
__global__ __launch_bounds__(256) void k_phi(const float* __restrict__ phi,
                                             const float2* __restrict__ TW,
                                             float2* __restrict__ Phi2) {
  extern __shared__ float2 buf[];
  int k = blockIdx.x, tid = threadIdx.x;
  const float scale = 2.0f / 8192.0f;
  for (int r = tid; r < 4096; r += 256) {
    buf[r + (r >> 4)] = float2{phi[(2 * r) * K_F + k] * scale, 0.0f};
    int r2i = r + 4096;
    buf[r2i + (r2i >> 4)] = float2{0.0f, 0.0f};
  }
  pass_r8t<10, -1, 256>(buf, TW + TW1024, tid);
  pass_r8t<7, -1, 256>(buf, TW + TW128, tid);
  pass_r8t<4, -1, 256>(buf, TW + TW16, tid);
  pass_r8t<1, -1, 256>(buf, TW + TW2, tid);
  __syncthreads();
  for (int j = tid; j < 4096; j += 256) {  // forward radix-2 (h=1)
    float2* p = buf + (2 * j + ((2 * j) >> 4));
    float2 u = p[0], v = p[1];
    p[0] = float2{u.x + v.x, u.y + v.y};
    p[1] = float2{u.x - v.x, u.y - v.y};
  }
  __syncthreads();
  for (int f = tid; f < NFFT2; f += 256) Phi2[k * NFFT2 + f] = buf[f + (f >> 4)];
}

// W2[d][f] = sum_k Mf[k][d] * Phi2[k][f]  (packed bf16 re|im)
__global__ __launch_bounds__(256) void k_w2(const float2* __restrict__ Phi2,
                                            const float* __restrict__ Mf,
                                            uint32_t* __restrict__ W2) {
  __shared__ float2 p[K_F][256];
  __shared__ float mf[K_F][32];
  int tid = threadIdx.x;
  int fc = blockIdx.x & 31, dc = blockIdx.x >> 5;
  int f0 = fc * 256, d0 = dc * 32;
  for (int i = tid; i < K_F * 256; i += 256) {
    int k = i >> 8, fl = i & 255;
    p[k][fl] = Phi2[k * NFFT2 + f0 + fl];
  }
  for (int i = tid; i < K_F * 32; i += 256) {
    int k = i >> 5, dl = i & 31;
    mf[k][dl] = Mf[k * D_CH + d0 + dl];
  }
  __syncthreads();
  for (int dl = 0; dl < 32; ++dl) {
    float re = 0.f, im = 0.f;
#pragma unroll
    for (int k = 0; k < K_F; ++k) {
      float m = mf[k][dl];
      re += m * p[k][tid].x;
      im += m * p[k][tid].y;
    }
    W2[(size_t)(d0 + dl) * NFFT2 + f0 + tid] = packbf2(re, im);
  }
}

// ---------- bf16 MFMA GEMM, 2-deep B / 3-deep A pipeline, counted vmcnt ----------
__device__ __forceinline__ void gload_lds16(const void* g, void* l) {
  __builtin_amdgcn_global_load_lds(
      (const __attribute__((address_space(1))) void*)g,
      (__attribute__((address_space(3))) void*)l, 16, 0, 0);
}

__global__ __launch_bounds__(512, 2) void k_gemm(const float* __restrict__ X,
                                                 const uint16_t* __restrict__ MiT,
                                                 uint16_t* __restrict__ Cp) {
  extern __shared__ char lds[];
  char* const As0 = lds;            // 2 x [128][64] bf16 = 2 x 16 KB
  char* const Bs0 = lds + 32768;    // 3 x [256][64] bf16 = 3 x 32 KB
  int tid = threadIdx.x;
  int lane = tid & 63, wid = tid >> 6;
  // bijective XCD swizzle: 768 wg = 8 XCD x 96; 3 bn-siblings of a bm share one XCD L2
  int pb = blockIdx.x;
  int v = (pb & 7) * 96 + (pb >> 3);
  int bm = v / 3, bn = v % 3;
  int m0 = bm * 128, n0 = bn * 256;
  int wr = wid >> 2, wc = wid & 3;  // 2 x 4 waves, per-wave 64x64 output
  int lm = lane & 15, lg = lane >> 4;
  f32x4 acc[4][4] = {};
  float4 fa[3][4];  // 3 in-flight A tiles (fp32 regs), static-indexed

#define STAGE_B(bufc, k0)                                              \
  _Pragma("unroll") for (int it = 0; it < 4; ++it) {                   \
    int s = it * 512 + tid;                                            \
    int row = s >> 3;                                                  \
    int cb = ((s & 7) << 4) ^ ((row & 7) << 4);                        \
    gload_lds16(MiT + (size_t)(n0 + row) * 768 + (k0) + (cb >> 1),     \
                Bs0 + (bufc) * 32768 + (it * 512 + wid * 64) * 16);    \
  }
#define LOAD_A(aset, k0)                                               \
  _Pragma("unroll") for (int jt = 0; jt < 2; ++jt) {                   \
    int s = jt * 512 + tid;                                            \
    int row = s >> 3, c16 = s & 7;                                     \
    const float* src = X + (size_t)(m0 + row) * 768 + (k0) + c16 * 8;  \
    fa[aset][2 * jt] = *(const float4*)src;                            \
    fa[aset][2 * jt + 1] = *(const float4*)(src + 4);                  \
  }
#define WRITE_A(abuf, aset)                                            \
  _Pragma("unroll") for (int jt = 0; jt < 2; ++jt) {                   \
    int s = jt * 512 + tid;                                            \
    int row = s >> 3, c16 = s & 7;                                     \
    uint4 o;                                                           \
    o.x = pkbf(fa[aset][2 * jt].x, fa[aset][2 * jt].y);                \
    o.y = pkbf(fa[aset][2 * jt].z, fa[aset][2 * jt].w);                \
    o.z = pkbf(fa[aset][2 * jt + 1].x, fa[aset][2 * jt + 1].y);        \
    o.w = pkbf(fa[aset][2 * jt + 1].z, fa[aset][2 * jt + 1].w);        \
    *(uint4*)(As0 + (abuf) * 16384 + row * 128 + ((c16 << 4) ^ ((row & 7) << 4))) = o; \
  }
#define RD_A(dst, abuf, kbyte)                                                              \
  _Pragma("unroll") for (int i = 0; i < 4; ++i) {                                           \
    int row = wr * 64 + i * 16 + lm;                                                        \
    dst[i] = *(const bf16x8*)(As0 + (abuf) * 16384 + row * 128 + ((kbyte) ^ ((row & 7) << 4))); \
  }
#define RD_B(dst, bufc, kbyte)                                                              \
  _Pragma("unroll") for (int i = 0; i < 4; ++i) {                                           \
    int row = wc * 64 + i * 16 + lm;                                                        \
    dst[i] = *(const bf16x8*)(Bs0 + (bufc) * 32768 + row * 128 + ((kbyte) ^ ((row & 7) << 4))); \
  }
#define MFMA16(av, bv)                                                        \
  _Pragma("unroll") for (int mi = 0; mi < 4; ++mi)                            \
  _Pragma("unroll") for (int ni = 0; ni < 4; ++ni)                            \
      acc[mi][ni] = __builtin_amdgcn_mfma_f32_16x16x32_bf16(av[mi], bv[ni], acc[mi][ni], 0, 0, 0);

  // ---- prologue: B 2-deep, A 3-deep ----
  STAGE_B(0, 0);      // B_0
  LOAD_A(0, 0);       // A_0
  STAGE_B(1, 64);     // B_1
  LOAD_A(1, 64);      // A_1
  LOAD_A(2, 128);     // A_2
  WRITE_A(0, 0);      // implicit vmcnt(12): retires B_0 + A_0
  asm volatile("s_waitcnt lgkmcnt(0)" ::: "memory");
  __builtin_amdgcn_s_barrier();

  int kb0 = lg * 16, kb1 = 64 + lg * 16;
#pragma unroll
  for (int kt = 0; kt < 12; ++kt) {
    // top-of-step prefetch issues (B for kt+2, A for kt+3)
    if (kt <= 9) STAGE_B((kt + 2) % 3, (kt + 2) * 64);
    if (kt <= 8) LOAD_A((kt + 3) % 3, (kt + 3) * 64);
    // phase 0
    {
      bf16x8 a0[4], b0[4];
      RD_A(a0, kt & 1, kb0);
      RD_B(b0, kt % 3, kb0);
      asm volatile("s_waitcnt lgkmcnt(0)" ::: "memory");
      __builtin_amdgcn_sched_barrier(0);
      __builtin_amdgcn_s_setprio(1);
      MFMA16(a0, b0);
      __builtin_amdgcn_s_setprio(0);
    }
    // phase 1
    {
      bf16x8 a1[4], b1[4];
      RD_A(a1, kt & 1, kb1);
      RD_B(b1, kt % 3, kb1);
      asm volatile("s_waitcnt lgkmcnt(0)" ::: "memory");
      __builtin_amdgcn_sched_barrier(0);
      __builtin_amdgcn_s_setprio(1);
      MFMA16(a1, b1);
      __builtin_amdgcn_s_setprio(0);
    }
    if (kt <= 10) {
      WRITE_A((kt + 1) & 1, (kt + 1) % 3);
      // counted drain: retire B_{kt+1} only; keep B_{kt+2}/A_{kt+2,3} in flight
      if (kt <= 8)      asm volatile("s_waitcnt vmcnt(12)" ::: "memory");
      else if (kt == 9) asm volatile("s_waitcnt vmcnt(8)" ::: "memory");
      else              asm volatile("s_waitcnt vmcnt(0)" ::: "memory");
      asm volatile("s_waitcnt lgkmcnt(0)" ::: "memory");
      __builtin_amdgcn_s_barrier();
    }
  }
#undef STAGE_B
#undef LOAD_A
#undef WRITE_A
#undef RD_A
#undef RD_B
#undef MFMA16

  // epilogue: write transposed (B,D,L) bf16, 4 t-contig per lane
#pragma unroll
  for (int mi = 0; mi < 4; ++mi) {
#pragma unroll
    for (int ni = 0; ni < 4; ++ni) {
      int mg = m0 + wr * 64 + mi * 16 + lg * 4;
      int dd = n0 + wc * 64 + ni * 16 + lm;
      int bb = mg >> 13, t = mg & 8191;
      f32x4 vv = acc[mi][ni];
      uint2 o;
      o.x = packbf2(vv[0], vv[1]);
      o.y = packbf2(vv[2], vv[3]);
      *(uint2*)(Cp + ((size_t)bb * 768 + dd) * 8192 + t) = o;
    }
  }
}

// ---------- per-(b,d) FFT conv ----------
__global__ __launch_bounds__(512, 4) void k_conv(const uint16_t* __restrict__ xprojT,
                                                 const uint32_t* __restrict__ W2,
                                                 const float2* __restrict__ TW,
                                                 uint16_t* __restrict__ convo) {
  extern __shared__ float2 buf[];
  int tid = threadIdx.x;
  int bd = blockIdx.x;  // b*768 + d
  int d = bd % 768;
  const uint32_t* row32 = (const uint32_t*)(xprojT + (size_t)bd * 8192);
  p1_fused(buf, row32, TW + TW1024, tid);
  pass_r8t<7, -1, 512>(buf, TW + TW128, tid);
  pass_r8t<4, -1, 512>(buf, TW + TW16, tid);
  pass_r8t<1, -1, 512>(buf, TW + TW2, tid);
  mid_fused(buf, W2 + (size_t)d * NFFT2, tid);
  pass_r8t<1, 1, 512>(buf, TW + TW2, tid);
  pass_r8t<4, 1, 512>(buf, TW + TW16, tid);
  pass_r8t<7, 1, 512>(buf, TW + TW128, tid);
  last_fused(buf, (uint32_t*)(convo + (size_t)bd * 8192), TW + TW1024, tid);
}

// ---------- transpose (B,D,L) bf16 -> (B,L,D) fp32 ----------
__global__ __launch_bounds__(256) void k_tr(const uint16_t* __restrict__ convo,
                                            float* __restrict__ out) {
  __shared__ uint16_t tile[64][72];
  int tid = threadIdx.x;
  int bx = blockIdx.x;
  int b = bx / 1536;
  int r = bx - b * 1536;
  int d0 = (r >> 7) << 6;
  int t0 = (r & 127) << 6;
  {
    int rr = tid >> 3;
    int c8 = (tid & 7) << 3;
#pragma unroll
    for (int p = 0; p < 2; ++p) {
      int row = p * 32 + rr;
      uint4 v = *(const uint4*)(convo + ((size_t)(b * 768 + d0 + row)) * 8192 + t0 + c8);
      *(uint4*)&tile[row][c8] = v;
    }
  }
  __syncthreads();
  {
    int c4 = (tid & 15) << 2;
    int tg = tid >> 4;
#pragma unroll
    for (int p = 0; p < 4; ++p) {
      int tt = p * 16 + tg;
      float4 o;
      o.x = __uint_as_float((uint32_t)tile[c4 + 0][tt] << 16);
      o.y = __uint_as_float((uint32_t)tile[c4 + 1][tt] << 16);
      o.z = __uint_as_float((uint32_t)tile[c4 + 2][tt] << 16);
      o.w = __uint_as_float((uint32_t)tile[c4 + 3][tt] << 16);
      *(float4*)(out + ((size_t)b * 8192 + t0 + tt) * 768 + d0 + c4) = o;
    }
  }
}

extern "C" void kernel_launch(void* const* d_in, const int* in_sizes, int n_in,
                              void* d_out, int out_size, void* d_ws, size_t ws_size,
                              hipStream_t stream) {
  const float* x   = (const float*)d_in[0];
  const float* phi = (const float*)d_in[1];
  const float* Mi  = (const float*)d_in[2];
  const float* Mf  = (const float*)d_in[3];
  float* out = (float*)d_out;

  // d_out staging: [0,75KB) twiddle table; [48MB,96MB) x_projT bf16 (B,D,L).
  // Both fully consumed before k_tr overwrites d_out.
  float2* TW = (float2*)d_out;
  uint16_t* xprojT = (uint16_t*)d_out + 25165824;

  char* ws = (char*)d_ws;
  uint16_t* convo = (uint16_t*)ws;               // 50,331,648 B  (B,D,L) bf16 conv result
  uint32_t* W2    = (uint32_t*)(ws + 50331648);  // 25,165,824 B  [768][8192] bf16 re|im
  float2*   Phi2  = (float2*)(ws + 75497472);    //  1,572,864 B  [24][8192] fp32 complex
  uint16_t* MiT   = (uint16_t*)(ws + 77070336);  //  1,179,648 B  [768][768] bf16

  k_tw<<<(TW_TOTAL + 255) / 256, 256, 0, stream>>>(TW);
  k_mit<<<2304, 256, 0, stream>>>(Mi, MiT);
  k_phi<<<24, 256, LDS_BYTES, stream>>>(phi, TW, Phi2);
  k_w2<<<768, 256, 0, stream>>>(Phi2, Mf, W2);
  k_gemm<<<768, 512, GEMM_LDS, stream>>>(x, MiT, xprojT);
  k_conv<<<3072, 512, LDS_BYTES, stream>>>(xprojT, W2, TW, convo);
  k_tr<<<6144, 256, 0, stream>>>(convo, out);
}

// Round 7
// 233.979 us; speedup vs baseline: 1.4415x; 1.4415x over previous
//
#include <hip/hip_runtime.h>
#include <stdint.h>

// Problem constants
#define B_SZ 4
#define L_SEQ 8192
#define D_CH 768
#define K_F 24
#define NFFT2 8192       // FFT size after parity split (2*4096)
#define LDS_BYTES 69632  // 8704 float2 (padded: phi(i) = i + (i>>4))
#define GEMM_LDS 131072  // As 2x16KB + Bs 3x32KB

typedef __attribute__((ext_vector_type(4))) float f32x4;
typedef __attribute__((ext_vector_type(8))) __bf16 bf16x8;

// ---------- bf16 helpers (RNE) ----------
__device__ __forceinline__ uint32_t f2bf1(float f) {
  uint32_t u = __float_as_uint(f);
  return (u + 0x7fffu + ((u >> 16) & 1u)) >> 16;
}
__device__ __forceinline__ uint32_t packbf2(float lo, float hi) {
  return f2bf1(lo) | (f2bf1(hi) << 16);
}
__device__ __forceinline__ float2 unpackbf2(uint32_t v) {
  return float2{__uint_as_float(v << 16), __uint_as_float(v & 0xffff0000u)};
}
__device__ __forceinline__ float2 cmulf(float2 a, float2 b) {
  return float2{a.x * b.x - a.y * b.y, a.x * b.y + a.y * b.x};
}
__device__ __forceinline__ uint32_t pkbf(float lo, float hi) {
  uint32_t r;
  asm("v_cvt_pk_bf16_f32 %0, %1, %2" : "=v"(r) : "v"(lo), "v"(hi));
  return r;
}

// MiT[n][e] = Mi[e][n], bf16
__global__ __launch_bounds__(256) void k_mit(const float* __restrict__ Mi,
                                             uint16_t* __restrict__ MiT) {
  int i = blockIdx.x * 256 + threadIdx.x;  // = n*768 + e
  int n = i / 768, e = i - n * 768;
  MiT[i] = (uint16_t)f2bf1(Mi[e * 768 + n]);
}

// ---------- radix-8 DFT building block ----------
// S=-1: forward (W8 = e^{-2pi i/8}); S=+1: inverse (unnormalized, W8^{-1})
template <int S>
__device__ __forceinline__ void dft8(float2* x) {
  const float C = 0.70710678118654752f;
  float2 t0{x[0].x + x[4].x, x[0].y + x[4].y}, t1{x[0].x - x[4].x, x[0].y - x[4].y};
  float2 t2{x[2].x + x[6].x, x[2].y + x[6].y}, t3{x[2].x - x[6].x, x[2].y - x[6].y};
  float2 t4{x[1].x + x[5].x, x[1].y + x[5].y}, t5{x[1].x - x[5].x, x[1].y - x[5].y};
  float2 t6{x[3].x + x[7].x, x[3].y + x[7].y}, t7{x[3].x - x[7].x, x[3].y - x[7].y};
  float2 t3r = (S < 0) ? float2{t3.y, -t3.x} : float2{-t3.y, t3.x};
  float2 t7r = (S < 0) ? float2{t7.y, -t7.x} : float2{-t7.y, t7.x};
  float2 e0{t0.x + t2.x, t0.y + t2.y}, e2{t0.x - t2.x, t0.y - t2.y};
  float2 e1{t1.x + t3r.x, t1.y + t3r.y}, e3{t1.x - t3r.x, t1.y - t3r.y};
  float2 o0{t4.x + t6.x, t4.y + t6.y}, o2{t4.x - t6.x, t4.y - t6.y};
  float2 o1{t5.x + t7r.x, t5.y + t7r.y}, o3{t5.x - t7r.x, t5.y - t7r.y};
  float2 o1r = (S < 0) ? float2{C * (o1.x + o1.y), C * (o1.y - o1.x)}
                       : float2{C * (o1.x - o1.y), C * (o1.y + o1.x)};
  float2 o2r = (S < 0) ? float2{o2.y, -o2.x} : float2{-o2.y, o2.x};
  float2 o3r = (S < 0) ? float2{C * (o3.y - o3.x), -C * (o3.x + o3.y)}
                       : float2{-C * (o3.x + o3.y), C * (o3.x - o3.y)};
  x[0] = float2{e0.x + o0.x, e0.y + o0.y};
  x[4] = float2{e0.x - o0.x, e0.y - o0.y};
  x[1] = float2{e1.x + o1r.x, e1.y + o1r.y};
  x[5] = float2{e1.x - o1r.x, e1.y - o1r.y};
  x[2] = float2{e2.x + o2r.x, e2.y + o2r.y};
  x[6] = float2{e2.x - o2r.x, e2.y - o2r.y};
  x[3] = float2{e3.x + o3r.x, e3.y + o3r.y};
  x[7] = float2{e3.x - o3r.x, e3.y - o3r.y};
}

// Generic radix-8 LDS pass on padded layout, sincos twiddles. One address compute
// per butterfly; all 16 LDS accesses use compile-time immediate offsets (st = h + h/16).
template <int LH, int S, int NT>
__device__ __forceinline__ void pass_r8(float2* a, int tid) {
  constexpr int h = 1 << LH;
  constexpr int st = h + (h >> 4);
  const float ang = (S < 0 ? -6.2831853071795864769f : 6.2831853071795864769f) / (float)(h * 8);
  __syncthreads();
#pragma unroll
  for (int jj = 0; jj < 1024 / NT; ++jj) {
    int j = jj * NT + tid;
    int pos = j & (h - 1);
    int base = ((j >> LH) << (LH + 3)) + pos;
    float2* p = a + (base + (base >> 4));
    float2 x[8];
#pragma unroll
    for (int q = 0; q < 8; ++q) x[q] = p[q * st];
    float sn, cs;
    __sincosf(ang * (float)pos, &sn, &cs);
    float2 w{cs, sn};
    if constexpr (S < 0) {
      dft8<-1>(x);
      float2 wq = w;
      x[1] = cmulf(x[1], wq);
#pragma unroll
      for (int q = 2; q < 8; ++q) {
        wq = cmulf(wq, w);
        x[q] = cmulf(x[q], wq);
      }
    } else {
      float2 wq = w;
      x[1] = cmulf(x[1], wq);
#pragma unroll
      for (int q = 2; q < 8; ++q) {
        wq = cmulf(wq, w);
        x[q] = cmulf(x[q], wq);
      }
      dft8<1>(x);
    }
#pragma unroll
    for (int q = 0; q < 8; ++q) p[q * st] = x[q];
  }
}

// Fused first forward pass (h=1024): read packed bf16 row from global, upper half zero.
__device__ __forceinline__ void p1_fused(float2* a, const uint32_t* __restrict__ row32, int tid) {
#pragma unroll
  for (int jj = 0; jj < 2; ++jj) {
    int j = jj * 512 + tid;
    float2 x[8];
#pragma unroll
    for (int q = 0; q < 4; ++q) x[q] = unpackbf2(row32[j + q * 1024]);
    x[4] = x[5] = x[6] = x[7] = float2{0.f, 0.f};  // const-folded through dft8
    dft8<-1>(x);
    float sn, cs;
    __sincosf(-6.2831853071795864769f / 8192.0f * (float)j, &sn, &cs);
    float2 w{cs, sn}, wq = w;
    x[1] = cmulf(x[1], wq);
#pragma unroll
    for (int q = 2; q < 8; ++q) {
      wq = cmulf(wq, w);
      x[q] = cmulf(x[q], wq);
    }
    float2* p = a + (j + (j >> 4));
#pragma unroll
    for (int q = 0; q < 8; ++q) p[q * 1088] = x[q];
  }
}

// In-register fused middle: fwd radix-8(h=2) + fwd r2 + xW2 + inv r2 + inv radix-8(h=2).
// Each thread owns 16 consecutive points (padded layout: pad(16m+i) = 17m+i).
// h=2 twiddles are compile-time constants W16^q — zero transcendentals here.
__device__ __forceinline__ void mid16(float2* a, const uint32_t* __restrict__ wrow, int tid) {
  const float C1 = 0.92387953251128675613f, S1 = 0.38268343236508977173f;
  const float C2 = 0.70710678118654752440f;
  __syncthreads();
#pragma unroll
  for (int jj = 0; jj < 2; ++jj) {
    int m = jj * 512 + tid;
    float2* p = a + 17 * m;  // 16 consecutive padded entries
    float2 e[8], o[8];
#pragma unroll
    for (int q = 0; q < 8; ++q) {
      e[q] = p[2 * q];
      o[q] = p[2 * q + 1];
    }
    // forward radix-8, h=2: even butterfly (pos=0, unity), odd (pos=1, W16^q)
    dft8<-1>(e);
    dft8<-1>(o);
    o[1] = cmulf(o[1], float2{C1, -S1});
    o[2] = cmulf(o[2], float2{C2, -C2});
    o[3] = cmulf(o[3], float2{S1, -C1});
    o[4] = float2{o[4].y, -o[4].x};
    o[5] = cmulf(o[5], float2{-S1, -C1});
    o[6] = cmulf(o[6], float2{-C2, -C2});
    o[7] = cmulf(o[7], float2{-C1, -S1});
    // fwd r2 (pairs 2q,2q+1) + xW2 + inv r2
    const uint4* wp = (const uint4*)(wrow + 16 * m);
    uint4 w0 = wp[0], w1 = wp[1], w2 = wp[2], w3 = wp[3];
    uint32_t wv[16] = {w0.x, w0.y, w0.z, w0.w, w1.x, w1.y, w1.z, w1.w,
                       w2.x, w2.y, w2.z, w2.w, w3.x, w3.y, w3.z, w3.w};
#pragma unroll
    for (int q = 0; q < 8; ++q) {
      float2 s{e[q].x + o[q].x, e[q].y + o[q].y};
      float2 d{e[q].x - o[q].x, e[q].y - o[q].y};
      s = cmulf(s, unpackbf2(wv[2 * q]));
      d = cmulf(d, unpackbf2(wv[2 * q + 1]));
      e[q] = float2{s.x + d.x, s.y + d.y};
      o[q] = float2{s.x - d.x, s.y - d.y};
    }
    // inverse radix-8, h=2: conj twiddle odd, then idft8
    o[1] = cmulf(o[1], float2{C1, S1});
    o[2] = cmulf(o[2], float2{C2, C2});
    o[3] = cmulf(o[3], float2{S1, C1});
    o[4] = float2{-o[4].y, o[4].x};
    o[5] = cmulf(o[5], float2{-S1, C1});
    o[6] = cmulf(o[6], float2{-C2, C2});
    o[7] = cmulf(o[7], float2{-C1, S1});
    dft8<1>(e);
    dft8<1>(o);
#pragma unroll
    for (int q = 0; q < 8; ++q) {
      p[2 * q] = e[q];
      p[2 * q + 1] = o[q];
    }
  }
}

// Fused last inverse pass (h=1024): pack bf16 + store; keep only first 4096 outputs.
__device__ __forceinline__ void last_fused(float2* a, uint32_t* __restrict__ out32, int tid) {
  __syncthreads();
#pragma unroll
  for (int jj = 0; jj < 2; ++jj) {
    int j = jj * 512 + tid;
    float2* p = a + (j + (j >> 4));
    float2 x[8];
#pragma unroll
    for (int q = 0; q < 8; ++q) x[q] = p[q * 1088];
    float sn, cs;
    __sincosf(6.2831853071795864769f / 8192.0f * (float)j, &sn, &cs);
    float2 w{cs, sn}, wq = w;
    x[1] = cmulf(x[1], wq);
#pragma unroll
    for (int q = 2; q < 8; ++q) {
      wq = cmulf(wq, w);
      x[q] = cmulf(x[q], wq);
    }
    dft8<1>(x);
#pragma unroll
    for (int q = 0; q < 4; ++q) out32[j + q * 1024] = packbf2(x[q].x, x[q].y);
  }
}

// Phi2[k][f] = fwd-FFT( pad( (2/8192)*phi[2r,k], r<4096 ) ), scrambled order (matches k_conv)
__global__ __launch_bounds__(256) void k_phi(const float* __restrict__ phi,
                                             float2* __restrict__ Phi2) {
  extern __shared__ float2 buf[];
  int k = blockIdx.x, tid = threadIdx.x;
  const float scale = 2.0f / 8192.0f;
  for (int r = tid; r < 4096; r += 256) {
    buf[r + (r >> 4)] = float2{phi[(2 * r) * K_F + k] * scale, 0.0f};
    int r2i = r + 4096;
    buf[r2i + (r2i >> 4)] = float2{0.0f, 0.0f};
  }
  pass_r8<10, -1, 256>(buf, tid);
  pass_r8<7, -1, 256>(buf, tid);
  pass_r8<4, -1, 256>(buf, tid);
  pass_r8<1, -1, 256>(buf, tid);
  __syncthreads();
  for (int j = tid; j < 4096; j += 256) {  // forward radix-2 (h=1)
    float2* p = buf + (2 * j + ((2 * j) >> 4));
    float2 u = p[0], v = p[1];
    p[0] = float2{u.x + v.x, u.y + v.y};
    p[1] = float2{u.x - v.x, u.y - v.y};
  }
  __syncthreads();
  for (int f = tid; f < NFFT2; f += 256) Phi2[k * NFFT2 + f] = buf[f + (f >> 4)];
}

// W2[d][f] = sum_k Mf[k][d] * Phi2[k][f]  (packed bf16 re|im)
__global__ __launch_bounds__(256) void k_w2(const float2* __restrict__ Phi2,
                                            const float* __restrict__ Mf,
                                            uint32_t* __restrict__ W2) {
  __shared__ float2 p[K_F][256];
  __shared__ float mf[K_F][32];
  int tid = threadIdx.x;
  int fc = blockIdx.x & 31, dc = blockIdx.x >> 5;
  int f0 = fc * 256, d0 = dc * 32;
  for (int i = tid; i < K_F * 256; i += 256) {
    int k = i >> 8, fl = i & 255;
    p[k][fl] = Phi2[k * NFFT2 + f0 + fl];
  }
  for (int i = tid; i < K_F * 32; i += 256) {
    int k = i >> 5, dl = i & 31;
    mf[k][dl] = Mf[k * D_CH + d0 + dl];
  }
  __syncthreads();
  for (int dl = 0; dl < 32; ++dl) {
    float re = 0.f, im = 0.f;
#pragma unroll
    for (int k = 0; k < K_F; ++k) {
      float m = mf[k][dl];
      re += m * p[k][tid].x;
      im += m * p[k][tid].y;
    }
    W2[(size_t)(d0 + dl) * NFFT2 + f0 + tid] = packbf2(re, im);
  }
}

// ---------- bf16 MFMA GEMM, 2-deep B / 3-deep A pipeline, counted vmcnt ----------
__device__ __forceinline__ void gload_lds16(const void* g, void* l) {
  __builtin_amdgcn_global_load_lds(
      (const __attribute__((address_space(1))) void*)g,
      (__attribute__((address_space(3))) void*)l, 16, 0, 0);
}

__global__ __launch_bounds__(512, 2) void k_gemm(const float* __restrict__ X,
                                                 const uint16_t* __restrict__ MiT,
                                                 uint16_t* __restrict__ Cp) {
  extern __shared__ char lds[];
  char* const As0 = lds;            // 2 x [128][64] bf16 = 2 x 16 KB
  char* const Bs0 = lds + 32768;    // 3 x [256][64] bf16 = 3 x 32 KB
  int tid = threadIdx.x;
  int lane = tid & 63, wid = tid >> 6;
  // bijective XCD swizzle: 768 wg = 8 XCD x 96; 3 bn-siblings of a bm share one XCD L2
  int pb = blockIdx.x;
  int v = (pb & 7) * 96 + (pb >> 3);
  int bm = v / 3, bn = v % 3;
  int m0 = bm * 128, n0 = bn * 256;
  int wr = wid >> 2, wc = wid & 3;  // 2 x 4 waves, per-wave 64x64 output
  int lm = lane & 15, lg = lane >> 4;
  f32x4 acc[4][4] = {};
  float4 fa[3][4];  // 3 in-flight A tiles (fp32 regs), static-indexed

#define STAGE_B(bufc, k0)                                              \
  _Pragma("unroll") for (int it = 0; it < 4; ++it) {                   \
    int s = it * 512 + tid;                                            \
    int row = s >> 3;                                                  \
    int cb = ((s & 7) << 4) ^ ((row & 7) << 4);                        \
    gload_lds16(MiT + (size_t)(n0 + row) * 768 + (k0) + (cb >> 1),     \
                Bs0 + (bufc) * 32768 + (it * 512 + wid * 64) * 16);    \
  }
#define LOAD_A(aset, k0)                                               \
  _Pragma("unroll") for (int jt = 0; jt < 2; ++jt) {                   \
    int s = jt * 512 + tid;                                            \
    int row = s >> 3, c16 = s & 7;                                     \
    const float* src = X + (size_t)(m0 + row) * 768 + (k0) + c16 * 8;  \
    fa[aset][2 * jt] = *(const float4*)src;                            \
    fa[aset][2 * jt + 1] = *(const float4*)(src + 4);                  \
  }
#define WRITE_A(abuf, aset)                                            \
  _Pragma("unroll") for (int jt = 0; jt < 2; ++jt) {                   \
    int s = jt * 512 + tid;                                            \
    int row = s >> 3, c16 = s & 7;                                     \
    uint4 o;                                                           \
    o.x = pkbf(fa[aset][2 * jt].x, fa[aset][2 * jt].y);                \
    o.y = pkbf(fa[aset][2 * jt].z, fa[aset][2 * jt].w);                \
    o.z = pkbf(fa[aset][2 * jt + 1].x, fa[aset][2 * jt + 1].y);        \
    o.w = pkbf(fa[aset][2 * jt + 1].z, fa[aset][2 * jt + 1].w);        \
    *(uint4*)(As0 + (abuf) * 16384 + row * 128 + ((c16 << 4) ^ ((row & 7) << 4))) = o; \
  }
#define RD_A(dst, abuf, kbyte)                                                              \
  _Pragma("unroll") for (int i = 0; i < 4; ++i) {                                           \
    int row = wr * 64 + i * 16 + lm;                                                        \
    dst[i] = *(const bf16x8*)(As0 + (abuf) * 16384 + row * 128 + ((kbyte) ^ ((row & 7) << 4))); \
  }
#define RD_B(dst, bufc, kbyte)                                                              \
  _Pragma("unroll") for (int i = 0; i < 4; ++i) {                                           \
    int row = wc * 64 + i * 16 + lm;                                                        \
    dst[i] = *(const bf16x8*)(Bs0 + (bufc) * 32768 + row * 128 + ((kbyte) ^ ((row & 7) << 4))); \
  }
#define MFMA16(av, bv)                                                        \
  _Pragma("unroll") for (int mi = 0; mi < 4; ++mi)                            \
  _Pragma("unroll") for (int ni = 0; ni < 4; ++ni)                            \
      acc[mi][ni] = __builtin_amdgcn_mfma_f32_16x16x32_bf16(av[mi], bv[ni], acc[mi][ni], 0, 0, 0);

  // ---- prologue: B 2-deep, A 3-deep ----
  STAGE_B(0, 0);      // B_0
  LOAD_A(0, 0);       // A_0
  STAGE_B(1, 64);     // B_1
  LOAD_A(1, 64);      // A_1
  LOAD_A(2, 128);     // A_2
  WRITE_A(0, 0);      // implicit vmcnt wait retires B_0 + A_0
  asm volatile("s_waitcnt lgkmcnt(0)" ::: "memory");
  __builtin_amdgcn_s_barrier();

  int kb0 = lg * 16, kb1 = 64 + lg * 16;
#pragma unroll
  for (int kt = 0; kt < 12; ++kt) {
    // top-of-step prefetch issues (B for kt+2, A for kt+3)
    if (kt <= 9) STAGE_B((kt + 2) % 3, (kt + 2) * 64);
    if (kt <= 8) LOAD_A((kt + 3) % 3, (kt + 3) * 64);
    // phase 0
    {
      bf16x8 a0[4], b0[4];
      RD_A(a0, kt & 1, kb0);
      RD_B(b0, kt % 3, kb0);
      asm volatile("s_waitcnt lgkmcnt(0)" ::: "memory");
      __builtin_amdgcn_sched_barrier(0);
      __builtin_amdgcn_s_setprio(1);
      MFMA16(a0, b0);
      __builtin_amdgcn_s_setprio(0);
    }
    // phase 1
    {
      bf16x8 a1[4], b1[4];
      RD_A(a1, kt & 1, kb1);
      RD_B(b1, kt % 3, kb1);
      asm volatile("s_waitcnt lgkmcnt(0)" ::: "memory");
      __builtin_amdgcn_sched_barrier(0);
      __builtin_amdgcn_s_setprio(1);
      MFMA16(a1, b1);
      __builtin_amdgcn_s_setprio(0);
    }
    if (kt <= 10) {
      WRITE_A((kt + 1) & 1, (kt + 1) % 3);
      // counted drain: retire B_{kt+1} only; keep B_{kt+2}/A_{kt+2,3} in flight
      if (kt <= 8)      asm volatile("s_waitcnt vmcnt(12)" ::: "memory");
      else if (kt == 9) asm volatile("s_waitcnt vmcnt(8)" ::: "memory");
      else              asm volatile("s_waitcnt vmcnt(0)" ::: "memory");
      asm volatile("s_waitcnt lgkmcnt(0)" ::: "memory");
      __builtin_amdgcn_s_barrier();
    }
  }
#undef STAGE_B
#undef LOAD_A
#undef WRITE_A
#undef RD_A
#undef RD_B
#undef MFMA16

  // epilogue: write transposed (B,D,L) bf16, 4 t-contig per lane
#pragma unroll
  for (int mi = 0; mi < 4; ++mi) {
#pragma unroll
    for (int ni = 0; ni < 4; ++ni) {
      int mg = m0 + wr * 64 + mi * 16 + lg * 4;
      int dd = n0 + wc * 64 + ni * 16 + lm;
      int bb = mg >> 13, t = mg & 8191;
      f32x4 vv = acc[mi][ni];
      uint2 o;
      o.x = packbf2(vv[0], vv[1]);
      o.y = packbf2(vv[2], vv[3]);
      *(uint2*)(Cp + ((size_t)bb * 768 + dd) * 8192 + t) = o;
    }
  }
}

// ---------- per-(b,d) FFT conv: 7-pass pipeline with in-register fused middle ----------
__global__ __launch_bounds__(512, 4) void k_conv(const uint16_t* __restrict__ xprojT,
                                                 const uint32_t* __restrict__ W2,
                                                 uint16_t* __restrict__ convo) {
  extern __shared__ float2 buf[];
  int tid = threadIdx.x;
  int bd = blockIdx.x;  // b*768 + d
  int d = bd % 768;
  const uint32_t* row32 = (const uint32_t*)(xprojT + (size_t)bd * 8192);
  p1_fused(buf, row32, tid);
  pass_r8<7, -1, 512>(buf, tid);
  pass_r8<4, -1, 512>(buf, tid);
  mid16(buf, W2 + (size_t)d * NFFT2, tid);
  pass_r8<4, 1, 512>(buf, tid);
  pass_r8<7, 1, 512>(buf, tid);
  last_fused(buf, (uint32_t*)(convo + (size_t)bd * 8192), tid);
}

// ---------- transpose (B,D,L) bf16 -> (B,L,D) fp32 ----------
__global__ __launch_bounds__(256) void k_tr(const uint16_t* __restrict__ convo,
                                            float* __restrict__ out) {
  __shared__ uint16_t tile[64][72];
  int tid = threadIdx.x;
  int bx = blockIdx.x;
  int b = bx / 1536;
  int r = bx - b * 1536;
  int d0 = (r >> 7) << 6;
  int t0 = (r & 127) << 6;
  {
    int rr = tid >> 3;
    int c8 = (tid & 7) << 3;
#pragma unroll
    for (int p = 0; p < 2; ++p) {
      int row = p * 32 + rr;
      uint4 v = *(const uint4*)(convo + ((size_t)(b * 768 + d0 + row)) * 8192 + t0 + c8);
      *(uint4*)&tile[row][c8] = v;
    }
  }
  __syncthreads();
  {
    int c4 = (tid & 15) << 2;
    int tg = tid >> 4;
#pragma unroll
    for (int p = 0; p < 4; ++p) {
      int tt = p * 16 + tg;
      float4 o;
      o.x = __uint_as_float((uint32_t)tile[c4 + 0][tt] << 16);
      o.y = __uint_as_float((uint32_t)tile[c4 + 1][tt] << 16);
      o.z = __uint_as_float((uint32_t)tile[c4 + 2][tt] << 16);
      o.w = __uint_as_float((uint32_t)tile[c4 + 3][tt] << 16);
      *(float4*)(out + ((size_t)b * 8192 + t0 + tt) * 768 + d0 + c4) = o;
    }
  }
}

extern "C" void kernel_launch(void* const* d_in, const int* in_sizes, int n_in,
                              void* d_out, int out_size, void* d_ws, size_t ws_size,
                              hipStream_t stream) {
  const float* x   = (const float*)d_in[0];
  const float* phi = (const float*)d_in[1];
  const float* Mi  = (const float*)d_in[2];
  const float* Mf  = (const float*)d_in[3];
  float* out = (float*)d_out;

  // d_out doubles as staging: [48MB,96MB) x_projT bf16 (B,D,L); [0,48MB) unused until k_tr
  uint16_t* xprojT = (uint16_t*)d_out + 25165824;

  char* ws = (char*)d_ws;
  uint16_t* convo = (uint16_t*)ws;               // 50,331,648 B  (B,D,L) bf16 conv result
  uint32_t* W2    = (uint32_t*)(ws + 50331648);  // 25,165,824 B  [768][8192] bf16 re|im
  float2*   Phi2  = (float2*)(ws + 75497472);    //  1,572,864 B  [24][8192] fp32 complex
  uint16_t* MiT   = (uint16_t*)(ws + 77070336);  //  1,179,648 B  [768][768] bf16

  k_mit<<<2304, 256, 0, stream>>>(Mi, MiT);
  k_phi<<<24, 256, LDS_BYTES, stream>>>(phi, Phi2);
  k_w2<<<768, 256, 0, stream>>>(Phi2, Mf, W2);
  k_gemm<<<768, 512, GEMM_LDS, stream>>>(x, MiT, xprojT);
  k_conv<<<3072, 512, LDS_BYTES, stream>>>(xprojT, W2, convo);
  k_tr<<<6144, 256, 0, stream>>>(convo, out);
}

// Round 8
// 215.221 us; speedup vs baseline: 1.5671x; 1.0872x over previous
//
#include <hip/hip_runtime.h>
#include <stdint.h>

// Problem constants
#define B_SZ 4
#define L_SEQ 8192
#define D_CH 768
#define K_F 24
#define NFFT2 8192       // FFT size after parity split (2*4096)
#define LDS_BYTES 69632  // 8704 float2 (padded: phi(i) = i + (i>>4))
#define GEMM_LDS 131072  // As 2x16KB + Bs 3x32KB

typedef __attribute__((ext_vector_type(4))) float f32x4;
typedef __attribute__((ext_vector_type(8))) __bf16 bf16x8;

// ---------- bf16 helpers (RNE) ----------
__device__ __forceinline__ uint32_t f2bf1(float f) {
  uint32_t u = __float_as_uint(f);
  return (u + 0x7fffu + ((u >> 16) & 1u)) >> 16;
}
__device__ __forceinline__ uint32_t packbf2(float lo, float hi) {
  return f2bf1(lo) | (f2bf1(hi) << 16);
}
__device__ __forceinline__ float2 unpackbf2(uint32_t v) {
  return float2{__uint_as_float(v << 16), __uint_as_float(v & 0xffff0000u)};
}
__device__ __forceinline__ float2 cmulf(float2 a, float2 b) {
  return float2{a.x * b.x - a.y * b.y, a.x * b.y + a.y * b.x};
}
__device__ __forceinline__ uint32_t pkbf(float lo, float hi) {
  uint32_t r;
  asm("v_cvt_pk_bf16_f32 %0, %1, %2" : "=v"(r) : "v"(lo), "v"(hi));
  return r;
}

// MiT[n][e] = Mi[e][n], bf16
__global__ __launch_bounds__(256) void k_mit(const float* __restrict__ Mi,
                                             uint16_t* __restrict__ MiT) {
  int i = blockIdx.x * 256 + threadIdx.x;  // = n*768 + e
  int n = i / 768, e = i - n * 768;
  MiT[i] = (uint16_t)f2bf1(Mi[e * 768 + n]);
}

// ---------- radix-8 DFT building block ----------
// S=-1: forward (W8 = e^{-2pi i/8}); S=+1: inverse (unnormalized, W8^{-1})
template <int S>
__device__ __forceinline__ void dft8(float2* x) {
  const float C = 0.70710678118654752f;
  float2 t0{x[0].x + x[4].x, x[0].y + x[4].y}, t1{x[0].x - x[4].x, x[0].y - x[4].y};
  float2 t2{x[2].x + x[6].x, x[2].y + x[6].y}, t3{x[2].x - x[6].x, x[2].y - x[6].y};
  float2 t4{x[1].x + x[5].x, x[1].y + x[5].y}, t5{x[1].x - x[5].x, x[1].y - x[5].y};
  float2 t6{x[3].x + x[7].x, x[3].y + x[7].y}, t7{x[3].x - x[7].x, x[3].y - x[7].y};
  float2 t3r = (S < 0) ? float2{t3.y, -t3.x} : float2{-t3.y, t3.x};
  float2 t7r = (S < 0) ? float2{t7.y, -t7.x} : float2{-t7.y, t7.x};
  float2 e0{t0.x + t2.x, t0.y + t2.y}, e2{t0.x - t2.x, t0.y - t2.y};
  float2 e1{t1.x + t3r.x, t1.y + t3r.y}, e3{t1.x - t3r.x, t1.y - t3r.y};
  float2 o0{t4.x + t6.x, t4.y + t6.y}, o2{t4.x - t6.x, t4.y - t6.y};
  float2 o1{t5.x + t7r.x, t5.y + t7r.y}, o3{t5.x - t7r.x, t5.y - t7r.y};
  float2 o1r = (S < 0) ? float2{C * (o1.x + o1.y), C * (o1.y - o1.x)}
                       : float2{C * (o1.x - o1.y), C * (o1.y + o1.x)};
  float2 o2r = (S < 0) ? float2{o2.y, -o2.x} : float2{-o2.y, o2.x};
  float2 o3r = (S < 0) ? float2{C * (o3.y - o3.x), -C * (o3.x + o3.y)}
                       : float2{-C * (o3.x + o3.y), C * (o3.x - o3.y)};
  x[0] = float2{e0.x + o0.x, e0.y + o0.y};
  x[4] = float2{e0.x - o0.x, e0.y - o0.y};
  x[1] = float2{e1.x + o1r.x, e1.y + o1r.y};
  x[5] = float2{e1.x - o1r.x, e1.y - o1r.y};
  x[2] = float2{e2.x + o2r.x, e2.y + o2r.y};
  x[6] = float2{e2.x - o2r.x, e2.y - o2r.y};
  x[3] = float2{e3.x + o3r.x, e3.y + o3r.y};
  x[7] = float2{e3.x - o3r.x, e3.y - o3r.y};
}

// Generic radix-8 LDS pass on padded layout, sincos twiddles. One address compute
// per butterfly; all 16 LDS accesses use compile-time immediate offsets (st = h + h/16).
template <int LH, int S, int NT>
__device__ __forceinline__ void pass_r8(float2* a, int tid) {
  constexpr int h = 1 << LH;
  constexpr int st = h + (h >> 4);
  const float ang = (S < 0 ? -6.2831853071795864769f : 6.2831853071795864769f) / (float)(h * 8);
  __syncthreads();
#pragma unroll
  for (int jj = 0; jj < 1024 / NT; ++jj) {
    int j = jj * NT + tid;
    int pos = j & (h - 1);
    int base = ((j >> LH) << (LH + 3)) + pos;
    float2* p = a + (base + (base >> 4));
    float2 x[8];
#pragma unroll
    for (int q = 0; q < 8; ++q) x[q] = p[q * st];
    float sn, cs;
    __sincosf(ang * (float)pos, &sn, &cs);
    float2 w{cs, sn};
    if constexpr (S < 0) {
      dft8<-1>(x);
      float2 wq = w;
      x[1] = cmulf(x[1], wq);
#pragma unroll
      for (int q = 2; q < 8; ++q) {
        wq = cmulf(wq, w);
        x[q] = cmulf(x[q], wq);
      }
    } else {
      float2 wq = w;
      x[1] = cmulf(x[1], wq);
#pragma unroll
      for (int q = 2; q < 8; ++q) {
        wq = cmulf(wq, w);
        x[q] = cmulf(x[q], wq);
      }
      dft8<1>(x);
    }
#pragma unroll
    for (int q = 0; q < 8; ++q) p[q * st] = x[q];
  }
}

// Fused first forward pass (h=1024): read packed bf16 row from global, upper half zero.
__device__ __forceinline__ void p1_fused(float2* a, const uint32_t* __restrict__ row32, int tid) {
#pragma unroll
  for (int jj = 0; jj < 2; ++jj) {
    int j = jj * 512 + tid;
    float2 x[8];
#pragma unroll
    for (int q = 0; q < 4; ++q) x[q] = unpackbf2(row32[j + q * 1024]);
    x[4] = x[5] = x[6] = x[7] = float2{0.f, 0.f};  // const-folded through dft8
    dft8<-1>(x);
    float sn, cs;
    __sincosf(-6.2831853071795864769f / 8192.0f * (float)j, &sn, &cs);
    float2 w{cs, sn}, wq = w;
    x[1] = cmulf(x[1], wq);
#pragma unroll
    for (int q = 2; q < 8; ++q) {
      wq = cmulf(wq, w);
      x[q] = cmulf(x[q], wq);
    }
    float2* p = a + (j + (j >> 4));
#pragma unroll
    for (int q = 0; q < 8; ++q) p[q * 1088] = x[q];
  }
}

// In-register fused middle: fwd radix-8(h=2) + fwd r2 + xW2 + inv r2 + inv radix-8(h=2).
// Each thread owns EXACTLY ONE group of 16 consecutive points (512 thr x 16 = 8192);
// padded layout: pad(16m+i) = 17m+i, max index 17*511+15 = 8702 < 8704.
// h=2 twiddles are compile-time constants W16^q — zero transcendentals here.
__device__ __forceinline__ void mid16(float2* a, const uint32_t* __restrict__ wrow, int tid) {
  const float C1 = 0.92387953251128675613f, S1 = 0.38268343236508977173f;
  const float C2 = 0.70710678118654752440f;
  __syncthreads();
  int m = tid;
  float2* p = a + 17 * m;  // 16 consecutive padded entries
  float2 e[8], o[8];
#pragma unroll
  for (int q = 0; q < 8; ++q) {
    e[q] = p[2 * q];
    o[q] = p[2 * q + 1];
  }
  // forward radix-8, h=2: even butterfly (pos=0, unity), odd (pos=1, W16^q)
  dft8<-1>(e);
  dft8<-1>(o);
  o[1] = cmulf(o[1], float2{C1, -S1});
  o[2] = cmulf(o[2], float2{C2, -C2});
  o[3] = cmulf(o[3], float2{S1, -C1});
  o[4] = float2{o[4].y, -o[4].x};
  o[5] = cmulf(o[5], float2{-S1, -C1});
  o[6] = cmulf(o[6], float2{-C2, -C2});
  o[7] = cmulf(o[7], float2{-C1, -S1});
  // fwd r2 (pairs 2q,2q+1) + xW2 + inv r2
  const uint4* wp = (const uint4*)(wrow + 16 * m);
  uint4 w0 = wp[0], w1 = wp[1], w2 = wp[2], w3 = wp[3];
  uint32_t wv[16] = {w0.x, w0.y, w0.z, w0.w, w1.x, w1.y, w1.z, w1.w,
                     w2.x, w2.y, w2.z, w2.w, w3.x, w3.y, w3.z, w3.w};
#pragma unroll
  for (int q = 0; q < 8; ++q) {
    float2 s{e[q].x + o[q].x, e[q].y + o[q].y};
    float2 d{e[q].x - o[q].x, e[q].y - o[q].y};
    s = cmulf(s, unpackbf2(wv[2 * q]));
    d = cmulf(d, unpackbf2(wv[2 * q + 1]));
    e[q] = float2{s.x + d.x, s.y + d.y};
    o[q] = float2{s.x - d.x, s.y - d.y};
  }
  // inverse radix-8, h=2: conj twiddle odd, then idft8
  o[1] = cmulf(o[1], float2{C1, S1});
  o[2] = cmulf(o[2], float2{C2, C2});
  o[3] = cmulf(o[3], float2{S1, C1});
  o[4] = float2{-o[4].y, o[4].x};
  o[5] = cmulf(o[5], float2{-S1, C1});
  o[6] = cmulf(o[6], float2{-C2, C2});
  o[7] = cmulf(o[7], float2{-C1, S1});
  dft8<1>(e);
  dft8<1>(o);
#pragma unroll
  for (int q = 0; q < 8; ++q) {
    p[2 * q] = e[q];
    p[2 * q + 1] = o[q];
  }
}

// Fused last inverse pass (h=1024): pack bf16 + store; keep only first 4096 outputs.
__device__ __forceinline__ void last_fused(float2* a, uint32_t* __restrict__ out32, int tid) {
  __syncthreads();
#pragma unroll
  for (int jj = 0; jj < 2; ++jj) {
    int j = jj * 512 + tid;
    float2* p = a + (j + (j >> 4));
    float2 x[8];
#pragma unroll
    for (int q = 0; q < 8; ++q) x[q] = p[q * 1088];
    float sn, cs;
    __sincosf(6.2831853071795864769f / 8192.0f * (float)j, &sn, &cs);
    float2 w{cs, sn}, wq = w;
    x[1] = cmulf(x[1], wq);
#pragma unroll
    for (int q = 2; q < 8; ++q) {
      wq = cmulf(wq, w);
      x[q] = cmulf(x[q], wq);
    }
    dft8<1>(x);
#pragma unroll
    for (int q = 0; q < 4; ++q) out32[j + q * 1024] = packbf2(x[q].x, x[q].y);
  }
}

// Phi2[k][f] = fwd-FFT( pad( (2/8192)*phi[2r,k], r<4096 ) ), scrambled order (matches k_conv)
__global__ __launch_bounds__(256) void k_phi(const float* __restrict__ phi,
                                             float2* __restrict__ Phi2) {
  extern __shared__ float2 buf[];
  int k = blockIdx.x, tid = threadIdx.x;
  const float scale = 2.0f / 8192.0f;
  for (int r = tid; r < 4096; r += 256) {
    buf[r + (r >> 4)] = float2{phi[(2 * r) * K_F + k] * scale, 0.0f};
    int r2i = r + 4096;
    buf[r2i + (r2i >> 4)] = float2{0.0f, 0.0f};
  }
  pass_r8<10, -1, 256>(buf, tid);
  pass_r8<7, -1, 256>(buf, tid);
  pass_r8<4, -1, 256>(buf, tid);
  pass_r8<1, -1, 256>(buf, tid);
  __syncthreads();
  for (int j = tid; j < 4096; j += 256) {  // forward radix-2 (h=1)
    float2* p = buf + (2 * j + ((2 * j) >> 4));
    float2 u = p[0], v = p[1];
    p[0] = float2{u.x + v.x, u.y + v.y};
    p[1] = float2{u.x - v.x, u.y - v.y};
  }
  __syncthreads();
  for (int f = tid; f < NFFT2; f += 256) Phi2[k * NFFT2 + f] = buf[f + (f >> 4)];
}

// W2[d][f] = sum_k Mf[k][d] * Phi2[k][f]  (packed bf16 re|im)
__global__ __launch_bounds__(256) void k_w2(const float2* __restrict__ Phi2,
                                            const float* __restrict__ Mf,
                                            uint32_t* __restrict__ W2) {
  __shared__ float2 p[K_F][256];
  __shared__ float mf[K_F][32];
  int tid = threadIdx.x;
  int fc = blockIdx.x & 31, dc = blockIdx.x >> 5;
  int f0 = fc * 256, d0 = dc * 32;
  for (int i = tid; i < K_F * 256; i += 256) {
    int k = i >> 8, fl = i & 255;
    p[k][fl] = Phi2[k * NFFT2 + f0 + fl];
  }
  for (int i = tid; i < K_F * 32; i += 256) {
    int k = i >> 5, dl = i & 31;
    mf[k][dl] = Mf[k * D_CH + d0 + dl];
  }
  __syncthreads();
  for (int dl = 0; dl < 32; ++dl) {
    float re = 0.f, im = 0.f;
#pragma unroll
    for (int k = 0; k < K_F; ++k) {
      float m = mf[k][dl];
      re += m * p[k][tid].x;
      im += m * p[k][tid].y;
    }
    W2[(size_t)(d0 + dl) * NFFT2 + f0 + tid] = packbf2(re, im);
  }
}

// ---------- bf16 MFMA GEMM, 2-deep B / 3-deep A pipeline, counted vmcnt ----------
__device__ __forceinline__ void gload_lds16(const void* g, void* l) {
  __builtin_amdgcn_global_load_lds(
      (const __attribute__((address_space(1))) void*)g,
      (__attribute__((address_space(3))) void*)l, 16, 0, 0);
}

__global__ __launch_bounds__(512, 2) void k_gemm(const float* __restrict__ X,
                                                 const uint16_t* __restrict__ MiT,
                                                 uint16_t* __restrict__ Cp) {
  extern __shared__ char lds[];
  char* const As0 = lds;            // 2 x [128][64] bf16 = 2 x 16 KB
  char* const Bs0 = lds + 32768;    // 3 x [256][64] bf16 = 3 x 32 KB
  int tid = threadIdx.x;
  int lane = tid & 63, wid = tid >> 6;
  // bijective XCD swizzle: 768 wg = 8 XCD x 96; 3 bn-siblings of a bm share one XCD L2
  int pb = blockIdx.x;
  int v = (pb & 7) * 96 + (pb >> 3);
  int bm = v / 3, bn = v % 3;
  int m0 = bm * 128, n0 = bn * 256;
  int wr = wid >> 2, wc = wid & 3;  // 2 x 4 waves, per-wave 64x64 output
  int lm = lane & 15, lg = lane >> 4;
  f32x4 acc[4][4] = {};
  float4 fa[3][4];  // 3 in-flight A tiles (fp32 regs), static-indexed

#define STAGE_B(bufc, k0)                                              \
  _Pragma("unroll") for (int it = 0; it < 4; ++it) {                   \
    int s = it * 512 + tid;                                            \
    int row = s >> 3;                                                  \
    int cb = ((s & 7) << 4) ^ ((row & 7) << 4);                        \
    gload_lds16(MiT + (size_t)(n0 + row) * 768 + (k0) + (cb >> 1),     \
                Bs0 + (bufc) * 32768 + (it * 512 + wid * 64) * 16);    \
  }
#define LOAD_A(aset, k0)                                               \
  _Pragma("unroll") for (int jt = 0; jt < 2; ++jt) {                   \
    int s = jt * 512 + tid;                                            \
    int row = s >> 3, c16 = s & 7;                                     \
    const float* src = X + (size_t)(m0 + row) * 768 + (k0) + c16 * 8;  \
    fa[aset][2 * jt] = *(const float4*)src;                            \
    fa[aset][2 * jt + 1] = *(const float4*)(src + 4);                  \
  }
#define WRITE_A(abuf, aset)                                            \
  _Pragma("unroll") for (int jt = 0; jt < 2; ++jt) {                   \
    int s = jt * 512 + tid;                                            \
    int row = s >> 3, c16 = s & 7;                                     \
    uint4 o;                                                           \
    o.x = pkbf(fa[aset][2 * jt].x, fa[aset][2 * jt].y);                \
    o.y = pkbf(fa[aset][2 * jt].z, fa[aset][2 * jt].w);                \
    o.z = pkbf(fa[aset][2 * jt + 1].x, fa[aset][2 * jt + 1].y);        \
    o.w = pkbf(fa[aset][2 * jt + 1].z, fa[aset][2 * jt + 1].w);        \
    *(uint4*)(As0 + (abuf) * 16384 + row * 128 + ((c16 << 4) ^ ((row & 7) << 4))) = o; \
  }
#define RD_A(dst, abuf, kbyte)                                                              \
  _Pragma("unroll") for (int i = 0; i < 4; ++i) {                                           \
    int row = wr * 64 + i * 16 + lm;                                                        \
    dst[i] = *(const bf16x8*)(As0 + (abuf) * 16384 + row * 128 + ((kbyte) ^ ((row & 7) << 4))); \
  }
#define RD_B(dst, bufc, kbyte)                                                              \
  _Pragma("unroll") for (int i = 0; i < 4; ++i) {                                           \
    int row = wc * 64 + i * 16 + lm;                                                        \
    dst[i] = *(const bf16x8*)(Bs0 + (bufc) * 32768 + row * 128 + ((kbyte) ^ ((row & 7) << 4))); \
  }
#define MFMA16(av, bv)                                                        \
  _Pragma("unroll") for (int mi = 0; mi < 4; ++mi)                            \
  _Pragma("unroll") for (int ni = 0; ni < 4; ++ni)                            \
      acc[mi][ni] = __builtin_amdgcn_mfma_f32_16x16x32_bf16(av[mi], bv[ni], acc[mi][ni], 0, 0, 0);

  // ---- prologue: B 2-deep, A 3-deep ----
  STAGE_B(0, 0);      // B_0
  LOAD_A(0, 0);       // A_0
  STAGE_B(1, 64);     // B_1
  LOAD_A(1, 64);      // A_1
  LOAD_A(2, 128);     // A_2
  WRITE_A(0, 0);      // implicit vmcnt wait retires B_0 + A_0
  asm volatile("s_waitcnt lgkmcnt(0)" ::: "memory");
  __builtin_amdgcn_s_barrier();

  int kb0 = lg * 16, kb1 = 64 + lg * 16;
#pragma unroll
  for (int kt = 0; kt < 12; ++kt) {
    // top-of-step prefetch issues (B for kt+2, A for kt+3)
    if (kt <= 9) STAGE_B((kt + 2) % 3, (kt + 2) * 64);
    if (kt <= 8) LOAD_A((kt + 3) % 3, (kt + 3) * 64);
    // phase 0
    {
      bf16x8 a0[4], b0[4];
      RD_A(a0, kt & 1, kb0);
      RD_B(b0, kt % 3, kb0);
      asm volatile("s_waitcnt lgkmcnt(0)" ::: "memory");
      __builtin_amdgcn_sched_barrier(0);
      __builtin_amdgcn_s_setprio(1);
      MFMA16(a0, b0);
      __builtin_amdgcn_s_setprio(0);
    }
    // phase 1
    {
      bf16x8 a1[4], b1[4];
      RD_A(a1, kt & 1, kb1);
      RD_B(b1, kt % 3, kb1);
      asm volatile("s_waitcnt lgkmcnt(0)" ::: "memory");
      __builtin_amdgcn_sched_barrier(0);
      __builtin_amdgcn_s_setprio(1);
      MFMA16(a1, b1);
      __builtin_amdgcn_s_setprio(0);
    }
    if (kt <= 10) {
      WRITE_A((kt + 1) & 1, (kt + 1) % 3);
      // counted drain: retire B_{kt+1} only; keep B_{kt+2}/A_{kt+2,3} in flight
      if (kt <= 8)      asm volatile("s_waitcnt vmcnt(12)" ::: "memory");
      else if (kt == 9) asm volatile("s_waitcnt vmcnt(8)" ::: "memory");
      else              asm volatile("s_waitcnt vmcnt(0)" ::: "memory");
      asm volatile("s_waitcnt lgkmcnt(0)" ::: "memory");
      __builtin_amdgcn_s_barrier();
    }
  }
#undef STAGE_B
#undef LOAD_A
#undef WRITE_A
#undef RD_A
#undef RD_B
#undef MFMA16

  // epilogue: write transposed (B,D,L) bf16, 4 t-contig per lane
#pragma unroll
  for (int mi = 0; mi < 4; ++mi) {
#pragma unroll
    for (int ni = 0; ni < 4; ++ni) {
      int mg = m0 + wr * 64 + mi * 16 + lg * 4;
      int dd = n0 + wc * 64 + ni * 16 + lm;
      int bb = mg >> 13, t = mg & 8191;
      f32x4 vv = acc[mi][ni];
      uint2 o;
      o.x = packbf2(vv[0], vv[1]);
      o.y = packbf2(vv[2], vv[3]);
      *(uint2*)(Cp + ((size_t)bb * 768 + dd) * 8192 + t) = o;
    }
  }
}

// ---------- per-(b,d) FFT conv: 7-pass pipeline with in-register fused middle ----------
__global__ __launch_bounds__(512, 4) void k_conv(const uint16_t* __restrict__ xprojT,
                                                 const uint32_t* __restrict__ W2,
                                                 uint16_t* __restrict__ convo) {
  extern __shared__ float2 buf[];
  int tid = threadIdx.x;
  int bd = blockIdx.x;  // b*768 + d
  int d = bd % 768;
  const uint32_t* row32 = (const uint32_t*)(xprojT + (size_t)bd * 8192);
  p1_fused(buf, row32, tid);
  pass_r8<7, -1, 512>(buf, tid);
  pass_r8<4, -1, 512>(buf, tid);
  mid16(buf, W2 + (size_t)d * NFFT2, tid);
  pass_r8<4, 1, 512>(buf, tid);
  pass_r8<7, 1, 512>(buf, tid);
  last_fused(buf, (uint32_t*)(convo + (size_t)bd * 8192), tid);
}

// ---------- transpose (B,D,L) bf16 -> (B,L,D) fp32 ----------
__global__ __launch_bounds__(256) void k_tr(const uint16_t* __restrict__ convo,
                                            float* __restrict__ out) {
  __shared__ uint16_t tile[64][72];
  int tid = threadIdx.x;
  int bx = blockIdx.x;
  int b = bx / 1536;
  int r = bx - b * 1536;
  int d0 = (r >> 7) << 6;
  int t0 = (r & 127) << 6;
  {
    int rr = tid >> 3;
    int c8 = (tid & 7) << 3;
#pragma unroll
    for (int p = 0; p < 2; ++p) {
      int row = p * 32 + rr;
      uint4 v = *(const uint4*)(convo + ((size_t)(b * 768 + d0 + row)) * 8192 + t0 + c8);
      *(uint4*)&tile[row][c8] = v;
    }
  }
  __syncthreads();
  {
    int c4 = (tid & 15) << 2;
    int tg = tid >> 4;
#pragma unroll
    for (int p = 0; p < 4; ++p) {
      int tt = p * 16 + tg;
      float4 o;
      o.x = __uint_as_float((uint32_t)tile[c4 + 0][tt] << 16);
      o.y = __uint_as_float((uint32_t)tile[c4 + 1][tt] << 16);
      o.z = __uint_as_float((uint32_t)tile[c4 + 2][tt] << 16);
      o.w = __uint_as_float((uint32_t)tile[c4 + 3][tt] << 16);
      *(float4*)(out + ((size_t)b * 8192 + t0 + tt) * 768 + d0 + c4) = o;
    }
  }
}

extern "C" void kernel_launch(void* const* d_in, const int* in_sizes, int n_in,
                              void* d_out, int out_size, void* d_ws, size_t ws_size,
                              hipStream_t stream) {
  const float* x   = (const float*)d_in[0];
  const float* phi = (const float*)d_in[1];
  const float* Mi  = (const float*)d_in[2];
  const float* Mf  = (const float*)d_in[3];
  float* out = (float*)d_out;

  // d_out doubles as staging: [48MB,96MB) x_projT bf16 (B,D,L); [0,48MB) unused until k_tr
  uint16_t* xprojT = (uint16_t*)d_out + 25165824;

  char* ws = (char*)d_ws;
  uint16_t* convo = (uint16_t*)ws;               // 50,331,648 B  (B,D,L) bf16 conv result
  uint32_t* W2    = (uint32_t*)(ws + 50331648);  // 25,165,824 B  [768][8192] bf16 re|im
  float2*   Phi2  = (float2*)(ws + 75497472);    //  1,572,864 B  [24][8192] fp32 complex
  uint16_t* MiT   = (uint16_t*)(ws + 77070336);  //  1,179,648 B  [768][768] bf16

  k_mit<<<2304, 256, 0, stream>>>(Mi, MiT);
  k_phi<<<24, 256, LDS_BYTES, stream>>>(phi, Phi2);
  k_w2<<<768, 256, 0, stream>>>(Phi2, Mf, W2);
  k_gemm<<<768, 512, GEMM_LDS, stream>>>(x, MiT, xprojT);
  k_conv<<<3072, 512, LDS_BYTES, stream>>>(xprojT, W2, convo);
  k_tr<<<6144, 256, 0, stream>>>(convo, out);
}

// Round 9
// 212.861 us; speedup vs baseline: 1.5845x; 1.0111x over previous
//
#include <hip/hip_runtime.h>
#include <stdint.h>

// Problem constants
#define B_SZ 4
#define L_SEQ 8192
#define D_CH 768
#define K_F 24
#define NFFT2 8192       // FFT size after parity split (2*4096)
#define LDS_BYTES 69632  // 8704 float2 (padded: phi(i) = i + (i>>4))
#define GEMM_LDS 81920   // As 2x16KB + Bs 3x16KB -> 2 blocks/CU

typedef __attribute__((ext_vector_type(4))) float f32x4;
typedef __attribute__((ext_vector_type(8))) __bf16 bf16x8;

// ---------- bf16 helpers (RNE) ----------
__device__ __forceinline__ uint32_t f2bf1(float f) {
  uint32_t u = __float_as_uint(f);
  return (u + 0x7fffu + ((u >> 16) & 1u)) >> 16;
}
__device__ __forceinline__ uint32_t packbf2(float lo, float hi) {
  return f2bf1(lo) | (f2bf1(hi) << 16);
}
__device__ __forceinline__ float2 unpackbf2(uint32_t v) {
  return float2{__uint_as_float(v << 16), __uint_as_float(v & 0xffff0000u)};
}
__device__ __forceinline__ float2 cmulf(float2 a, float2 b) {
  return float2{a.x * b.x - a.y * b.y, a.x * b.y + a.y * b.x};
}
__device__ __forceinline__ uint32_t pkbf(float lo, float hi) {
  uint32_t r;
  asm("v_cvt_pk_bf16_f32 %0, %1, %2" : "=v"(r) : "v"(lo), "v"(hi));
  return r;
}

// MiT[n][e] = Mi[e][n], bf16
__global__ __launch_bounds__(256) void k_mit(const float* __restrict__ Mi,
                                             uint16_t* __restrict__ MiT) {
  int i = blockIdx.x * 256 + threadIdx.x;  // = n*768 + e
  int n = i / 768, e = i - n * 768;
  MiT[i] = (uint16_t)f2bf1(Mi[e * 768 + n]);
}

// ---------- radix-8 DFT building block ----------
// S=-1: forward (W8 = e^{-2pi i/8}); S=+1: inverse (unnormalized, W8^{-1})
template <int S>
__device__ __forceinline__ void dft8(float2* x) {
  const float C = 0.70710678118654752f;
  float2 t0{x[0].x + x[4].x, x[0].y + x[4].y}, t1{x[0].x - x[4].x, x[0].y - x[4].y};
  float2 t2{x[2].x + x[6].x, x[2].y + x[6].y}, t3{x[2].x - x[6].x, x[2].y - x[6].y};
  float2 t4{x[1].x + x[5].x, x[1].y + x[5].y}, t5{x[1].x - x[5].x, x[1].y - x[5].y};
  float2 t6{x[3].x + x[7].x, x[3].y + x[7].y}, t7{x[3].x - x[7].x, x[3].y - x[7].y};
  float2 t3r = (S < 0) ? float2{t3.y, -t3.x} : float2{-t3.y, t3.x};
  float2 t7r = (S < 0) ? float2{t7.y, -t7.x} : float2{-t7.y, t7.x};
  float2 e0{t0.x + t2.x, t0.y + t2.y}, e2{t0.x - t2.x, t0.y - t2.y};
  float2 e1{t1.x + t3r.x, t1.y + t3r.y}, e3{t1.x - t3r.x, t1.y - t3r.y};
  float2 o0{t4.x + t6.x, t4.y + t6.y}, o2{t4.x - t6.x, t4.y - t6.y};
  float2 o1{t5.x + t7r.x, t5.y + t7r.y}, o3{t5.x - t7r.x, t5.y - t7r.y};
  float2 o1r = (S < 0) ? float2{C * (o1.x + o1.y), C * (o1.y - o1.x)}
                       : float2{C * (o1.x - o1.y), C * (o1.y + o1.x)};
  float2 o2r = (S < 0) ? float2{o2.y, -o2.x} : float2{-o2.y, o2.x};
  float2 o3r = (S < 0) ? float2{C * (o3.y - o3.x), -C * (o3.x + o3.y)}
                       : float2{-C * (o3.x + o3.y), C * (o3.x - o3.y)};
  x[0] = float2{e0.x + o0.x, e0.y + o0.y};
  x[4] = float2{e0.x - o0.x, e0.y - o0.y};
  x[1] = float2{e1.x + o1r.x, e1.y + o1r.y};
  x[5] = float2{e1.x - o1r.x, e1.y - o1r.y};
  x[2] = float2{e2.x + o2r.x, e2.y + o2r.y};
  x[6] = float2{e2.x - o2r.x, e2.y - o2r.y};
  x[3] = float2{e3.x + o3r.x, e3.y + o3r.y};
  x[7] = float2{e3.x - o3r.x, e3.y - o3r.y};
}

// Generic radix-8 LDS pass on padded layout, sincos twiddles. One address compute
// per butterfly; all 16 LDS accesses use compile-time immediate offsets (st = h + h/16).
template <int LH, int S, int NT>
__device__ __forceinline__ void pass_r8(float2* a, int tid) {
  constexpr int h = 1 << LH;
  constexpr int st = h + (h >> 4);
  const float ang = (S < 0 ? -6.2831853071795864769f : 6.2831853071795864769f) / (float)(h * 8);
  __syncthreads();
#pragma unroll
  for (int jj = 0; jj < 1024 / NT; ++jj) {
    int j = jj * NT + tid;
    int pos = j & (h - 1);
    int base = ((j >> LH) << (LH + 3)) + pos;
    float2* p = a + (base + (base >> 4));
    float2 x[8];
#pragma unroll
    for (int q = 0; q < 8; ++q) x[q] = p[q * st];
    float sn, cs;
    __sincosf(ang * (float)pos, &sn, &cs);
    float2 w{cs, sn};
    if constexpr (S < 0) {
      dft8<-1>(x);
      float2 wq = w;
      x[1] = cmulf(x[1], wq);
#pragma unroll
      for (int q = 2; q < 8; ++q) {
        wq = cmulf(wq, w);
        x[q] = cmulf(x[q], wq);
      }
    } else {
      float2 wq = w;
      x[1] = cmulf(x[1], wq);
#pragma unroll
      for (int q = 2; q < 8; ++q) {
        wq = cmulf(wq, w);
        x[q] = cmulf(x[q], wq);
      }
      dft8<1>(x);
    }
#pragma unroll
    for (int q = 0; q < 8; ++q) p[q * st] = x[q];
  }
}

// Fused first forward pass (h=1024): read packed bf16 row from global, upper half zero.
__device__ __forceinline__ void p1_fused(float2* a, const uint32_t* __restrict__ row32, int tid) {
#pragma unroll
  for (int jj = 0; jj < 2; ++jj) {
    int j = jj * 512 + tid;
    float2 x[8];
#pragma unroll
    for (int q = 0; q < 4; ++q) x[q] = unpackbf2(row32[j + q * 1024]);
    x[4] = x[5] = x[6] = x[7] = float2{0.f, 0.f};  // const-folded through dft8
    dft8<-1>(x);
    float sn, cs;
    __sincosf(-6.2831853071795864769f / 8192.0f * (float)j, &sn, &cs);
    float2 w{cs, sn}, wq = w;
    x[1] = cmulf(x[1], wq);
#pragma unroll
    for (int q = 2; q < 8; ++q) {
      wq = cmulf(wq, w);
      x[q] = cmulf(x[q], wq);
    }
    float2* p = a + (j + (j >> 4));
#pragma unroll
    for (int q = 0; q < 8; ++q) p[q * 1088] = x[q];
  }
}

// In-register fused middle: fwd radix-8(h=2) + fwd r2 + xW2 + inv r2 + inv radix-8(h=2).
// Each thread owns EXACTLY ONE group of 16 consecutive points (512 thr x 16 = 8192);
// padded layout: pad(16m+i) = 17m+i, max index 17*511+15 = 8702 < 8704.
// h=2 twiddles are compile-time constants W16^q — zero transcendentals here.
__device__ __forceinline__ void mid16(float2* a, const uint32_t* __restrict__ wrow, int tid) {
  const float C1 = 0.92387953251128675613f, S1 = 0.38268343236508977173f;
  const float C2 = 0.70710678118654752440f;
  __syncthreads();
  int m = tid;
  float2* p = a + 17 * m;  // 16 consecutive padded entries
  float2 e[8], o[8];
#pragma unroll
  for (int q = 0; q < 8; ++q) {
    e[q] = p[2 * q];
    o[q] = p[2 * q + 1];
  }
  // forward radix-8, h=2: even butterfly (pos=0, unity), odd (pos=1, W16^q)
  dft8<-1>(e);
  dft8<-1>(o);
  o[1] = cmulf(o[1], float2{C1, -S1});
  o[2] = cmulf(o[2], float2{C2, -C2});
  o[3] = cmulf(o[3], float2{S1, -C1});
  o[4] = float2{o[4].y, -o[4].x};
  o[5] = cmulf(o[5], float2{-S1, -C1});
  o[6] = cmulf(o[6], float2{-C2, -C2});
  o[7] = cmulf(o[7], float2{-C1, -S1});
  // fwd r2 (pairs 2q,2q+1) + xW2 + inv r2
  const uint4* wp = (const uint4*)(wrow + 16 * m);
  uint4 w0 = wp[0], w1 = wp[1], w2 = wp[2], w3 = wp[3];
  uint32_t wv[16] = {w0.x, w0.y, w0.z, w0.w, w1.x, w1.y, w1.z, w1.w,
                     w2.x, w2.y, w2.z, w2.w, w3.x, w3.y, w3.z, w3.w};
#pragma unroll
  for (int q = 0; q < 8; ++q) {
    float2 s{e[q].x + o[q].x, e[q].y + o[q].y};
    float2 d{e[q].x - o[q].x, e[q].y - o[q].y};
    s = cmulf(s, unpackbf2(wv[2 * q]));
    d = cmulf(d, unpackbf2(wv[2 * q + 1]));
    e[q] = float2{s.x + d.x, s.y + d.y};
    o[q] = float2{s.x - d.x, s.y - d.y};
  }
  // inverse radix-8, h=2: conj twiddle odd, then idft8
  o[1] = cmulf(o[1], float2{C1, S1});
  o[2] = cmulf(o[2], float2{C2, C2});
  o[3] = cmulf(o[3], float2{S1, C1});
  o[4] = float2{-o[4].y, o[4].x};
  o[5] = cmulf(o[5], float2{-S1, C1});
  o[6] = cmulf(o[6], float2{-C2, C2});
  o[7] = cmulf(o[7], float2{-C1, S1});
  dft8<1>(e);
  dft8<1>(o);
#pragma unroll
  for (int q = 0; q < 8; ++q) {
    p[2 * q] = e[q];
    p[2 * q + 1] = o[q];
  }
}

// Fused last inverse pass (h=1024): pack bf16 + store; keep only first 4096 outputs.
__device__ __forceinline__ void last_fused(float2* a, uint32_t* __restrict__ out32, int tid) {
  __syncthreads();
#pragma unroll
  for (int jj = 0; jj < 2; ++jj) {
    int j = jj * 512 + tid;
    float2* p = a + (j + (j >> 4));
    float2 x[8];
#pragma unroll
    for (int q = 0; q < 8; ++q) x[q] = p[q * 1088];
    float sn, cs;
    __sincosf(6.2831853071795864769f / 8192.0f * (float)j, &sn, &cs);
    float2 w{cs, sn}, wq = w;
    x[1] = cmulf(x[1], wq);
#pragma unroll
    for (int q = 2; q < 8; ++q) {
      wq = cmulf(wq, w);
      x[q] = cmulf(x[q], wq);
    }
    dft8<1>(x);
#pragma unroll
    for (int q = 0; q < 4; ++q) out32[j + q * 1024] = packbf2(x[q].x, x[q].y);
  }
}

// Phi2[k][f] = fwd-FFT( pad( (2/8192)*phi[2r,k], r<4096 ) ), scrambled order (matches k_conv)
__global__ __launch_bounds__(256) void k_phi(const float* __restrict__ phi,
                                             float2* __restrict__ Phi2) {
  extern __shared__ float2 buf[];
  int k = blockIdx.x, tid = threadIdx.x;
  const float scale = 2.0f / 8192.0f;
  for (int r = tid; r < 4096; r += 256) {
    buf[r + (r >> 4)] = float2{phi[(2 * r) * K_F + k] * scale, 0.0f};
    int r2i = r + 4096;
    buf[r2i + (r2i >> 4)] = float2{0.0f, 0.0f};
  }
  pass_r8<10, -1, 256>(buf, tid);
  pass_r8<7, -1, 256>(buf, tid);
  pass_r8<4, -1, 256>(buf, tid);
  pass_r8<1, -1, 256>(buf, tid);
  __syncthreads();
  for (int j = tid; j < 4096; j += 256) {  // forward radix-2 (h=1)
    float2* p = buf + (2 * j + ((2 * j) >> 4));
    float2 u = p[0], v = p[1];
    p[0] = float2{u.x + v.x, u.y + v.y};
    p[1] = float2{u.x - v.x, u.y - v.y};
  }
  __syncthreads();
  for (int f = tid; f < NFFT2; f += 256) Phi2[k * NFFT2 + f] = buf[f + (f >> 4)];
}

// W2[d][f] = sum_k Mf[k][d] * Phi2[k][f]  (packed bf16 re|im)
__global__ __launch_bounds__(256) void k_w2(const float2* __restrict__ Phi2,
                                            const float* __restrict__ Mf,
                                            uint32_t* __restrict__ W2) {
  __shared__ float2 p[K_F][256];
  __shared__ float mf[K_F][32];
  int tid = threadIdx.x;
  int fc = blockIdx.x & 31, dc = blockIdx.x >> 5;
  int f0 = fc * 256, d0 = dc * 32;
  for (int i = tid; i < K_F * 256; i += 256) {
    int k = i >> 8, fl = i & 255;
    p[k][fl] = Phi2[k * NFFT2 + f0 + fl];
  }
  for (int i = tid; i < K_F * 32; i += 256) {
    int k = i >> 5, dl = i & 31;
    mf[k][dl] = Mf[k * D_CH + d0 + dl];
  }
  __syncthreads();
  for (int dl = 0; dl < 32; ++dl) {
    float re = 0.f, im = 0.f;
#pragma unroll
    for (int k = 0; k < K_F; ++k) {
      float m = mf[k][dl];
      re += m * p[k][tid].x;
      im += m * p[k][tid].y;
    }
    W2[(size_t)(d0 + dl) * NFFT2 + f0 + tid] = packbf2(re, im);
  }
}

// ---------- bf16 MFMA GEMM: 128x128 tile, 256 thr, 2 blocks/CU, counted vmcnt ----------
__device__ __forceinline__ void gload_lds16(const void* g, void* l) {
  __builtin_amdgcn_global_load_lds(
      (const __attribute__((address_space(1))) void*)g,
      (__attribute__((address_space(3))) void*)l, 16, 0, 0);
}

__global__ __launch_bounds__(256, 2) void k_gemm(const float* __restrict__ X,
                                                 const uint16_t* __restrict__ MiT,
                                                 uint16_t* __restrict__ Cp) {
  extern __shared__ char lds[];
  char* const As0 = lds;            // 2 x [128][64] bf16 = 2 x 16 KB
  char* const Bs0 = lds + 32768;    // 3 x [128][64] bf16 = 3 x 16 KB
  int tid = threadIdx.x;
  int lane = tid & 63, wid = tid >> 6;
  // bijective XCD swizzle: 1536 wg = 8 XCD x 192; 6 bn-siblings of a bm share one XCD L2
  int pb = blockIdx.x;
  int v = (pb & 7) * 192 + (pb >> 3);
  int bm = v / 6, bn = v % 6;
  int m0 = bm * 128, n0 = bn * 128;
  int wr = wid >> 1, wc = wid & 1;  // 2 x 2 waves, per-wave 64x64 output
  int lm = lane & 15, lg = lane >> 4;
  f32x4 acc[4][4] = {};
  float4 fa[2][8];  // 2 in-flight A tiles (fp32 regs), static-indexed

// A loads issued BEFORE B each step: WRITE_A's implicit vmcnt drains only A (oldest),
// keeping B's in flight for the counted wait.
#define LOAD_A(aset, k0)                                               \
  _Pragma("unroll") for (int jt = 0; jt < 4; ++jt) {                   \
    int s = jt * 256 + tid;                                            \
    int row = s >> 3, c8 = s & 7;                                      \
    const float* src = X + (size_t)(m0 + row) * 768 + (k0) + c8 * 8;   \
    fa[aset][2 * jt] = *(const float4*)src;                            \
    fa[aset][2 * jt + 1] = *(const float4*)(src + 4);                  \
  }
#define STAGE_B(bufc, k0)                                              \
  _Pragma("unroll") for (int it = 0; it < 4; ++it) {                   \
    int s = it * 256 + tid;                                            \
    int row = s >> 3;                                                  \
    int cb = ((s & 7) << 4) ^ ((row & 7) << 4);                        \
    gload_lds16(MiT + (size_t)(n0 + row) * 768 + (k0) + (cb >> 1),     \
                Bs0 + (bufc) * 16384 + (it * 256 + wid * 64) * 16);    \
  }
#define WRITE_A(abuf, aset)                                            \
  _Pragma("unroll") for (int jt = 0; jt < 4; ++jt) {                   \
    int s = jt * 256 + tid;                                            \
    int row = s >> 3, c16 = s & 7;                                     \
    uint4 o;                                                           \
    o.x = pkbf(fa[aset][2 * jt].x, fa[aset][2 * jt].y);                \
    o.y = pkbf(fa[aset][2 * jt].z, fa[aset][2 * jt].w);                \
    o.z = pkbf(fa[aset][2 * jt + 1].x, fa[aset][2 * jt + 1].y);        \
    o.w = pkbf(fa[aset][2 * jt + 1].z, fa[aset][2 * jt + 1].w);        \
    *(uint4*)(As0 + (abuf) * 16384 + row * 128 + ((c16 << 4) ^ ((row & 7) << 4))) = o; \
  }
#define RD_A(dst, abuf, kbyte)                                                              \
  _Pragma("unroll") for (int i = 0; i < 4; ++i) {                                           \
    int row = wr * 64 + i * 16 + lm;                                                        \
    dst[i] = *(const bf16x8*)(As0 + (abuf) * 16384 + row * 128 + ((kbyte) ^ ((row & 7) << 4))); \
  }
#define RD_B(dst, bufc, kbyte)                                                              \
  _Pragma("unroll") for (int i = 0; i < 4; ++i) {                                           \
    int row = wc * 64 + i * 16 + lm;                                                        \
    dst[i] = *(const bf16x8*)(Bs0 + (bufc) * 16384 + row * 128 + ((kbyte) ^ ((row & 7) << 4))); \
  }
#define MFMA16(av, bv)                                                        \
  _Pragma("unroll") for (int mi = 0; mi < 4; ++mi)                            \
  _Pragma("unroll") for (int ni = 0; ni < 4; ++ni)                            \
      acc[mi][ni] = __builtin_amdgcn_mfma_f32_16x16x32_bf16(av[mi], bv[ni], acc[mi][ni], 0, 0, 0);

  // ---- prologue (issue order: A0, B0, A1, B1) ----
  LOAD_A(0, 0);       // A_0 (8 loads)
  STAGE_B(0, 0);      // B_0 (4)
  LOAD_A(1, 64);      // A_1 (8)
  STAGE_B(1, 64);     // B_1 (4)
  WRITE_A(0, 0);      // implicit vmcnt drains A_0 only
  asm volatile("s_waitcnt vmcnt(12)" ::: "memory");  // drain B_0; keep A_1+B_1
  asm volatile("s_waitcnt lgkmcnt(0)" ::: "memory");
  __builtin_amdgcn_s_barrier();

  int kb0 = lg * 16, kb1 = 64 + lg * 16;
#pragma unroll
  for (int kt = 0; kt < 12; ++kt) {
    // top-of-step prefetch (A then B, for tile kt+2)
    if (kt <= 9) {
      LOAD_A(kt & 1, (kt + 2) * 64);
      STAGE_B((kt + 2) % 3, (kt + 2) * 64);
    }
    // phase 0
    {
      bf16x8 a0[4], b0[4];
      RD_A(a0, kt & 1, kb0);
      RD_B(b0, kt % 3, kb0);
      asm volatile("s_waitcnt lgkmcnt(0)" ::: "memory");
      __builtin_amdgcn_sched_barrier(0);
      __builtin_amdgcn_s_setprio(1);
      MFMA16(a0, b0);
      __builtin_amdgcn_s_setprio(0);
    }
    // phase 1
    {
      bf16x8 a1[4], b1[4];
      RD_A(a1, kt & 1, kb1);
      RD_B(b1, kt % 3, kb1);
      asm volatile("s_waitcnt lgkmcnt(0)" ::: "memory");
      __builtin_amdgcn_sched_barrier(0);
      __builtin_amdgcn_s_setprio(1);
      MFMA16(a1, b1);
      __builtin_amdgcn_s_setprio(0);
    }
    if (kt <= 10) {
      WRITE_A((kt + 1) & 1, (kt + 1) & 1);  // implicit vmcnt drains A_{kt+1}
      // counted drain: retire B_{kt+1}; keep A_{kt+2}(8) + B_{kt+2}(4) in flight
      if (kt <= 9) asm volatile("s_waitcnt vmcnt(12)" ::: "memory");
      else         asm volatile("s_waitcnt vmcnt(0)" ::: "memory");
      asm volatile("s_waitcnt lgkmcnt(0)" ::: "memory");
      __builtin_amdgcn_s_barrier();
    }
  }
#undef LOAD_A
#undef STAGE_B
#undef WRITE_A
#undef RD_A
#undef RD_B
#undef MFMA16

  // epilogue: write transposed (B,D,L) bf16, 4 t-contig per lane
#pragma unroll
  for (int mi = 0; mi < 4; ++mi) {
#pragma unroll
    for (int ni = 0; ni < 4; ++ni) {
      int mg = m0 + wr * 64 + mi * 16 + lg * 4;
      int dd = n0 + wc * 64 + ni * 16 + lm;
      int bb = mg >> 13, t = mg & 8191;
      f32x4 vv = acc[mi][ni];
      uint2 o;
      o.x = packbf2(vv[0], vv[1]);
      o.y = packbf2(vv[2], vv[3]);
      *(uint2*)(Cp + ((size_t)bb * 768 + dd) * 8192 + t) = o;
    }
  }
}

// ---------- per-(b,d) FFT conv: 7-pass pipeline with in-register fused middle ----------
__global__ __launch_bounds__(512, 4) void k_conv(const uint16_t* __restrict__ xprojT,
                                                 const uint32_t* __restrict__ W2,
                                                 uint16_t* __restrict__ convo) {
  extern __shared__ float2 buf[];
  int tid = threadIdx.x;
  int bd = blockIdx.x;  // b*768 + d
  int d = bd % 768;
  const uint32_t* row32 = (const uint32_t*)(xprojT + (size_t)bd * 8192);
  p1_fused(buf, row32, tid);
  pass_r8<7, -1, 512>(buf, tid);
  pass_r8<4, -1, 512>(buf, tid);
  mid16(buf, W2 + (size_t)d * NFFT2, tid);
  pass_r8<4, 1, 512>(buf, tid);
  pass_r8<7, 1, 512>(buf, tid);
  last_fused(buf, (uint32_t*)(convo + (size_t)bd * 8192), tid);
}

// ---------- transpose (B,D,L) bf16 -> (B,L,D) fp32 ----------
__global__ __launch_bounds__(256) void k_tr(const uint16_t* __restrict__ convo,
                                            float* __restrict__ out) {
  __shared__ uint16_t tile[64][72];
  int tid = threadIdx.x;
  int bx = blockIdx.x;
  int b = bx / 1536;
  int r = bx - b * 1536;
  int d0 = (r >> 7) << 6;
  int t0 = (r & 127) << 6;
  {
    int rr = tid >> 3;
    int c8 = (tid & 7) << 3;
#pragma unroll
    for (int p = 0; p < 2; ++p) {
      int row = p * 32 + rr;
      uint4 v = *(const uint4*)(convo + ((size_t)(b * 768 + d0 + row)) * 8192 + t0 + c8);
      *(uint4*)&tile[row][c8] = v;
    }
  }
  __syncthreads();
  {
    int c4 = (tid & 15) << 2;
    int tg = tid >> 4;
#pragma unroll
    for (int p = 0; p < 4; ++p) {
      int tt = p * 16 + tg;
      float4 o;
      o.x = __uint_as_float((uint32_t)tile[c4 + 0][tt] << 16);
      o.y = __uint_as_float((uint32_t)tile[c4 + 1][tt] << 16);
      o.z = __uint_as_float((uint32_t)tile[c4 + 2][tt] << 16);
      o.w = __uint_as_float((uint32_t)tile[c4 + 3][tt] << 16);
      *(float4*)(out + ((size_t)b * 8192 + t0 + tt) * 768 + d0 + c4) = o;
    }
  }
}

extern "C" void kernel_launch(void* const* d_in, const int* in_sizes, int n_in,
                              void* d_out, int out_size, void* d_ws, size_t ws_size,
                              hipStream_t stream) {
  const float* x   = (const float*)d_in[0];
  const float* phi = (const float*)d_in[1];
  const float* Mi  = (const float*)d_in[2];
  const float* Mf  = (const float*)d_in[3];
  float* out = (float*)d_out;

  // d_out doubles as staging: [48MB,96MB) x_projT bf16 (B,D,L); [0,48MB) unused until k_tr
  uint16_t* xprojT = (uint16_t*)d_out + 25165824;

  char* ws = (char*)d_ws;
  uint16_t* convo = (uint16_t*)ws;               // 50,331,648 B  (B,D,L) bf16 conv result
  uint32_t* W2    = (uint32_t*)(ws + 50331648);  // 25,165,824 B  [768][8192] bf16 re|im
  float2*   Phi2  = (float2*)(ws + 75497472);    //  1,572,864 B  [24][8192] fp32 complex
  uint16_t* MiT   = (uint16_t*)(ws + 77070336);  //  1,179,648 B  [768][768] bf16

  k_mit<<<2304, 256, 0, stream>>>(Mi, MiT);
  k_phi<<<24, 256, LDS_BYTES, stream>>>(phi, Phi2);
  k_w2<<<768, 256, 0, stream>>>(Phi2, Mf, W2);
  k_gemm<<<1536, 256, GEMM_LDS, stream>>>(x, MiT, xprojT);
  k_conv<<<3072, 512, LDS_BYTES, stream>>>(xprojT, W2, convo);
  k_tr<<<6144, 256, 0, stream>>>(convo, out);
}